// Round 3
// baseline (238.568 us; speedup 1.0000x reference)
//
#include <hip/hip_runtime.h>

#define CCH 384
#define NHEADS 12
#define HDIM 32
#define NTOK 49
#define NWIN 1024
#define MROWS 50176
#define PSTR 72   // padded LDS stride for P tile (attn)

typedef __attribute__((ext_vector_type(8))) short bf16x8;
typedef __attribute__((ext_vector_type(4))) float f32x4;

#define WAITVM_BAR(N) asm volatile("s_waitcnt vmcnt(" #N ")\n\ts_barrier" ::: "memory")
#define BAR() asm volatile("s_barrier" ::: "memory")

__device__ __forceinline__ unsigned short f2bf(float f) {
    unsigned u = __builtin_bit_cast(unsigned, f);
    u += 0x7FFFu + ((u >> 16) & 1u);
    return (unsigned short)(u >> 16);
}

// async global -> LDS, 16B per lane. lds base must be wave-uniform.
__device__ __forceinline__ void g2lds16(const unsigned short* g, unsigned short* l) {
    __builtin_amdgcn_global_load_lds(
        (const __attribute__((address_space(1))) unsigned int*)g,
        (__attribute__((address_space(3))) unsigned int*)l,
        16, 0, 0);
}

// convert 8 f32 -> bf16x8 and store 16B to LDS (ds_write_b128)
__device__ __forceinline__ void st8(unsigned short* p, float4 a, float4 b) {
    bf16x8 v;
    v[0] = (short)f2bf(a.x); v[1] = (short)f2bf(a.y);
    v[2] = (short)f2bf(a.z); v[3] = (short)f2bf(a.w);
    v[4] = (short)f2bf(b.x); v[5] = (short)f2bf(b.y);
    v[6] = (short)f2bf(b.z); v[7] = (short)f2bf(b.w);
    *(bf16x8*)p = v;
}

// ---------------- prep: weights -> bf16, fused bias+mask table ----------------
__global__ void prep_kernel(const float* __restrict__ qkvw, const float* __restrict__ projw,
                            const float* __restrict__ rel_table,
                            unsigned short* __restrict__ wq, unsigned short* __restrict__ wp,
                            float* __restrict__ btt2) {
    int i = blockIdx.x * 256 + threadIdx.x;
    if (i < 3 * CCH * CCH) wq[i] = f2bf(qkvw[i]);
    if (i < CCH * CCH) wp[i] = f2bf(projw[i]);
    if (i < 4 * NHEADS * 16 * 64) {            // one float4 entry per thread
        int cls = i / (NHEADS * 16 * 64);
        int rem = i - cls * (NHEADS * 16 * 64);
        int h = rem / (16 * 64);
        int rem2 = rem - h * (16 * 64);
        int rb = rem2 >> 6, cj = rem2 & 63;
        int jreg = 0;
        if (cj < NTOK) {
            int jy = cj / 7, jx = cj - jy * 7;
            int ry = (cls & 2) ? ((jy < 4) ? 1 : 2) : 0;
            int rx = (cls & 1) ? ((jx < 4) ? 1 : 2) : 0;
            jreg = ry * 3 + rx;
        }
        float4 o;
        float* po = (float*)&o;
#pragma unroll
        for (int rr = 0; rr < 4; ++rr) {
            int ri = rb * 4 + rr;
            float v = -1e30f;
            if (ri < NTOK && cj < NTOK) {
                int iy = ri / 7, ix = ri - iy * 7;
                int jy = cj / 7, jx = cj - jy * 7;
                int idx = (iy - jy + 6) * 13 + (ix - jx + 6);
                v = rel_table[idx * NHEADS + h];
                int ry = (cls & 2) ? ((iy < 4) ? 1 : 2) : 0;
                int rx = (cls & 1) ? ((ix < 4) ? 1 : 2) : 0;
                if (ry * 3 + rx != jreg) v -= 100.f;
            }
            po[rr] = v;
        }
        *(float4*)&btt2[(size_t)i * 4] = o;
    }
}

// row -> source/dest pixel (roll by shift=3 folded in; same map both directions)
__device__ __forceinline__ size_t row_to_pixel(int r) {
    int wlin = r / 49, n = r - wlin * 49;
    int b = wlin >> 6, wimg = wlin & 63;
    int wy = wimg >> 3, wx = wimg & 7;
    int iy = n / 7, ix = n - iy * 7;
    int y = wy * 7 + iy + 3; if (y >= 56) y -= 56;
    int x = wx * 7 + ix + 3; if (x >= 56) x -= 56;
    return (size_t)((b * 56 + y) * 56 + x);
}

// ---------------- QKV GEMM: 256x128 tile, fused gather (A: f32 x -> reg -> swizzled LDS),
// single-barrier K-loop: st8(kk) -> drain -> barrier -> issue(kk+1) -> reads/MFMA ----------------
__global__ __launch_bounds__(512) void qkv_gemm(const float* __restrict__ xin,
        const unsigned short* __restrict__ wq, const float* __restrict__ qkv_bias,
        unsigned short* __restrict__ qb, unsigned short* __restrict__ kb,
        unsigned short* __restrict__ vb) {
    __shared__ unsigned short As[2][256 * 32];
    __shared__ unsigned short Bs[2][128 * 32];
    const int tid = threadIdx.x;
    // bijective XCD-chunk remap: nwg=1764, q=220, r=4 (m204 variant), col-fastest
    const int bid = blockIdx.x;
    const int xcd = bid & 7;
    const int base = (xcd < 4) ? xcd * 221 : (4 * 221 + (xcd - 4) * 220);
    const int swz = base + (bid >> 3);
    const int rb = swz / 9, cb = swz - rb * 9;
    const int row0 = rb * 256;
    const int col0 = cb * 128;
    const int lane = tid & 63, wv = tid >> 6;   // 8 waves
    const int wm = wv >> 1, wn = wv & 1;        // 4M x 2N, wave tile 64x64
    const int l15 = lane & 15, g = lane >> 4;

    // staging: per wave A = 32 rows (2 groups of 16) reg-staged from f32 x; B = 16 rows via DMA
    const int lrow = lane >> 2;                  // 0..15
    const int lc = lane & 3;                     // 16B chunk within 64B K-slice
    const int fk = (lrow >> 1) & 3;              // chunk swizzle key f(row)=(row>>1)&3 (row≡lrow mod 16-safe)
    const int rA0 = wv * 32 + lrow, rA1 = rA0 + 16;
    const float* gA0 = xin + row_to_pixel(row0 + rA0) * CCH + lc * 8;
    const float* gA1 = xin + row_to_pixel(row0 + rA1) * CCH + lc * 8;
    const int wo0 = rA0 * 32 + (lc ^ fk) * 8;    // write-side swizzled LDS chunk
    const int wo1 = rA1 * 32 + (lc ^ fk) * 8;
    // B: pre-swizzled global source chunk; LDS dest stays linear (g2lds16 requirement)
    const unsigned short* gB0 = wq + (size_t)(col0 + wv * 16 + lrow) * CCH + ((lc ^ fk) * 8);
    // fragment-read chunk: rows read are 16*k + l15 -> f = (l15>>1)&3 (constant per lane)
    const int rc = (g ^ ((l15 >> 1) & 3)) * 8;

    f32x4 acc[4][4];
#pragma unroll
    for (int i = 0; i < 4; ++i)
#pragma unroll
        for (int j = 0; j < 4; ++j) acc[i][j] = (f32x4){0.f, 0.f, 0.f, 0.f};

    // prologue: issue tile-0 loads (A to regs, B via DMA)
    float4 a0 = *(const float4*)(gA0);
    float4 a1 = *(const float4*)(gA0 + 4);
    float4 a2 = *(const float4*)(gA1);
    float4 a3 = *(const float4*)(gA1 + 4);
    g2lds16(gB0, &Bs[0][wv * 512]);

#pragma unroll
    for (int kk = 0; kk < 12; ++kk) {
        const int cur = kk & 1;
        // ---- top: commit tile kk to LDS, sync, then issue tile kk+1 ----
        asm volatile("s_waitcnt vmcnt(1)" ::: "memory");      // A(kk) regs landed (B(kk) DMA may fly)
        st8(&As[cur][wo0], a0, a1);
        st8(&As[cur][wo1], a2, a3);
        asm volatile("s_waitcnt vmcnt(0) lgkmcnt(0)\n\ts_barrier" ::: "memory");  // B(kk) + writes visible
        if (kk < 11) {   // issue AFTER barrier: DMA target (parity kk+1) provably not being read
            const int nxt = cur ^ 1;
            a0 = *(const float4*)(gA0 + (kk + 1) * 32);
            a1 = *(const float4*)(gA0 + (kk + 1) * 32 + 4);
            a2 = *(const float4*)(gA1 + (kk + 1) * 32);
            a3 = *(const float4*)(gA1 + (kk + 1) * 32 + 4);
            g2lds16(gB0 + (kk + 1) * 32, &Bs[nxt][wv * 512]);
        }
        // ---- body: fragment reads + MFMA (loads for kk+1 fly underneath) ----
        bf16x8 af[4], bfv[4];
#pragma unroll
        for (int mt = 0; mt < 4; ++mt)
            af[mt] = *(const bf16x8*)&As[cur][(wm * 64 + mt * 16 + l15) * 32 + rc];
#pragma unroll
        for (int nt = 0; nt < 4; ++nt)
            bfv[nt] = *(const bf16x8*)&Bs[cur][(wn * 64 + nt * 16 + l15) * 32 + rc];
#pragma unroll
        for (int mt = 0; mt < 4; ++mt)
#pragma unroll
            for (int nt = 0; nt < 4; ++nt)
                acc[mt][nt] = __builtin_amdgcn_mfma_f32_16x16x32_bf16(af[mt], bfv[nt], acc[mt][nt], 0, 0, 0);
    }

    // epilogue (R7 form): + bias; q scaled; coalesced [inst][tok][dim]
    const float SCALE = 0.17677669529663687f;
#pragma unroll
    for (int nt = 0; nt < 4; ++nt) {
        int col = col0 + wn * 64 + nt * 16 + l15;
        float bias = qkv_bias[col];
        int which = col / CCH;
        int rem = col - which * CCH;
        int h = rem >> 5, d = rem & 31;
        unsigned short* dstb = (which == 0) ? qb : ((which == 1) ? kb : vb);
        float scl = (which == 0) ? SCALE : 1.0f;
#pragma unroll
        for (int mt = 0; mt < 4; ++mt) {
#pragma unroll
            for (int rr = 0; rr < 4; ++rr) {
                int row = row0 + wm * 64 + mt * 16 + g * 4 + rr;
                int w2 = row / 49, n2 = row - w2 * 49;
                size_t inst = (size_t)(w2 * NHEADS + h);
                float v = (acc[mt][nt][rr] + bias) * scl;
                dstb[(inst * NTOK + n2) * HDIM + d] = f2bf(v);
            }
        }
    }
}

// ---------------- attention: one wave per (window, head); V via swizzled LDS ----------------
__global__ __launch_bounds__(256) void attn_kernel(const unsigned short* __restrict__ qbuf,
        const unsigned short* __restrict__ kbuf, const unsigned short* __restrict__ vbuf,
        const float* __restrict__ btt2, unsigned short* __restrict__ ao) {
    __shared__ unsigned short Ps[4][64 * PSTR];
    __shared__ unsigned short Vt[4][32 * 64];   // [d][tok] with XOR-swizzled tok
    const int tid = threadIdx.x;
    const int lane = tid & 63, wv = tid >> 6;
    const int inst = blockIdx.x * 4 + wv;
    const int w = inst / NHEADS, h = inst - w * NHEADS;
    const int l15 = lane & 15, g = lane >> 4;
    const unsigned short* qp = qbuf + (size_t)inst * (NTOK * HDIM);
    const unsigned short* kp = kbuf + (size_t)inst * (NTOK * HDIM);
    const unsigned short* vp = vbuf + (size_t)inst * (NTOK * HDIM);

    const bf16x8 zero8 = {0, 0, 0, 0, 0, 0, 0, 0};
    // early V prefetch (T14): 4x16B; masked zero for tok>=49 (NaN-safe)
    bf16x8 vpre[4];
#pragma unroll
    for (int p = 0; p < 4; ++p) {
        int e0 = (p * 64 + lane) * 8;           // 8 elems share one tok (e0 8-aligned)
        int tok = e0 >> 5;
        vpre[p] = (tok < NTOK) ? *(const bf16x8*)&vp[e0] : zero8;
    }

    bf16x8 aq[4], bk[4];
#pragma unroll
    for (int mt = 0; mt < 4; ++mt) {
        int row = mt * 16 + l15;
        aq[mt] = (row < NTOK) ? *(const bf16x8*)&qp[row * HDIM + g * 8] : zero8;
    }
#pragma unroll
    for (int nt = 0; nt < 4; ++nt) {
        int colk = nt * 16 + l15;
        bk[nt] = (colk < NTOK) ? *(const bf16x8*)&kp[colk * HDIM + g * 8] : zero8;
    }
    f32x4 s[4][4];
#pragma unroll
    for (int mt = 0; mt < 4; ++mt)
#pragma unroll
        for (int nt = 0; nt < 4; ++nt)
            s[mt][nt] = __builtin_amdgcn_mfma_f32_16x16x32_bf16(aq[mt], bk[nt], (f32x4){0.f, 0.f, 0.f, 0.f}, 0, 0, 0);

    // write V to swizzled LDS transpose while QK^T/softmax proceed
    {
        unsigned short* vt = Vt[wv];
#pragma unroll
        for (int p = 0; p < 4; ++p) {
            int e0 = (p * 64 + lane) * 8;
            int tok = e0 >> 5, d0 = e0 & 31;
#pragma unroll
            for (int j = 0; j < 8; ++j) {
                int d = d0 + j;
                vt[d * 64 + (tok ^ ((d & 7) << 3))] = (unsigned short)vpre[p][j];
            }
        }
    }

    // logits: (pre-scaled q)K^T + fused bias/mask table; coalesced float4 loads
    const int wimg = w & 63;
    const int wy = wimg >> 3, wx = wimg & 7;
    const int wcls = (((wy == 7) ? 2 : 0) | ((wx == 7) ? 1 : 0));
    const float4* bt4 = (const float4*)btt2 + ((size_t)(wcls * NHEADS + h)) * (16 * 64);

    float inv[4][4];
#pragma unroll
    for (int mt = 0; mt < 4; ++mt) {
        float4 bias4[4];
#pragma unroll
        for (int nt = 0; nt < 4; ++nt)
            bias4[nt] = bt4[(mt * 4 + g) * 64 + nt * 16 + l15];
#pragma unroll
        for (int rr = 0; rr < 4; ++rr) {
#pragma unroll
            for (int nt = 0; nt < 4; ++nt) {
                float bb = (rr == 0) ? bias4[nt].x : (rr == 1) ? bias4[nt].y : (rr == 2) ? bias4[nt].z : bias4[nt].w;
                s[mt][nt][rr] += bb;
            }
            // row softmax (16-lane butterfly)
            float m = fmaxf(fmaxf(s[mt][0][rr], s[mt][1][rr]), fmaxf(s[mt][2][rr], s[mt][3][rr]));
            m = fmaxf(m, __shfl_xor(m, 1));
            m = fmaxf(m, __shfl_xor(m, 2));
            m = fmaxf(m, __shfl_xor(m, 4));
            m = fmaxf(m, __shfl_xor(m, 8));
            float sum = 0.f;
#pragma unroll
            for (int nt = 0; nt < 4; ++nt) {
                float p = __expf(s[mt][nt][rr] - m);
                s[mt][nt][rr] = p;
                sum += p;
            }
            sum += __shfl_xor(sum, 1);
            sum += __shfl_xor(sum, 2);
            sum += __shfl_xor(sum, 4);
            sum += __shfl_xor(sum, 8);
            inv[mt][rr] = 1.0f / sum;
        }
    }
    // P -> LDS (re-fragment for PV)
    unsigned short* ps = Ps[wv];
#pragma unroll
    for (int mt = 0; mt < 4; ++mt)
#pragma unroll
        for (int nt = 0; nt < 4; ++nt)
#pragma unroll
            for (int rr = 0; rr < 4; ++rr)
                ps[(mt * 16 + g * 4 + rr) * PSTR + nt * 16 + l15] = f2bf(s[mt][nt][rr]);

    f32x4 o[4][2];
#pragma unroll
    for (int mt = 0; mt < 4; ++mt)
#pragma unroll
        for (int dt = 0; dt < 2; ++dt) o[mt][dt] = (f32x4){0.f, 0.f, 0.f, 0.f};

    const unsigned short* vt = Vt[wv];
#pragma unroll
    for (int kt = 0; kt < 2; ++kt) {
        bf16x8 ap[4];
#pragma unroll
        for (int mt = 0; mt < 4; ++mt)
            ap[mt] = *(const bf16x8*)&ps[(mt * 16 + l15) * PSTR + kt * 32 + g * 8];
#pragma unroll
        for (int dt = 0; dt < 2; ++dt) {
            const int d = dt * 16 + l15;
            const int cb = kt * 32 + g * 8;
            bf16x8 bv = *(const bf16x8*)&vt[d * 64 + (cb ^ ((d & 7) << 3))];
#pragma unroll
            for (int mt = 0; mt < 4; ++mt)
                o[mt][dt] = __builtin_amdgcn_mfma_f32_16x16x32_bf16(ap[mt], bv, o[mt][dt], 0, 0, 0);
        }
    }
    // write attn-out [M=50176][384] bf16
#pragma unroll
    for (int mt = 0; mt < 4; ++mt)
#pragma unroll
        for (int dt = 0; dt < 2; ++dt)
#pragma unroll
            for (int rr = 0; rr < 4; ++rr) {
                int row = mt * 16 + g * 4 + rr;
                if (row < NTOK) {
                    float val = o[mt][dt][rr] * inv[mt][rr];
                    ao[((size_t)(w * NTOK + row)) * CCH + h * HDIM + dt * 16 + l15] = f2bf(val);
                }
            }
}

// ---------------- proj GEMM: 128x128 tile, dbuf pipeline, fused scatter,
// bank-conflict swizzle via pre-swizzled g2lds16 source + swizzled reads ----------------
__global__ __launch_bounds__(256) void proj_gemm(const unsigned short* __restrict__ ain,
        const unsigned short* __restrict__ wp, const float* __restrict__ proj_bias,
        float* __restrict__ out) {
    __shared__ unsigned short As[2][128 * 32];
    __shared__ unsigned short Bs[2][128 * 32];
    const int tid = threadIdx.x;
    const int row0 = blockIdx.x * 128;
    const int col0 = blockIdx.y * 128;
    const int lane = tid & 63, wv = tid >> 6;
    const int wm = wv >> 1, wn = wv & 1;
    const int l15 = lane & 15, g = lane >> 4;

    const int srow = wv * 16 + (lane >> 2);               // group1 = +64, same f
    const int scs = (((lane & 3) ^ ((srow >> 1) & 3)) * 8);   // pre-swizzled source chunk
    const unsigned short* gA0 = ain + (size_t)(row0 + srow) * CCH + scs;
    const unsigned short* gA1 = gA0 + (size_t)64 * CCH;
    const unsigned short* gB0 = wp + (size_t)(col0 + srow) * CCH + scs;
    const unsigned short* gB1 = gB0 + (size_t)64 * CCH;
    const int rc = (g ^ ((l15 >> 1) & 3)) * 8;            // swizzled fragment-read chunk

    f32x4 acc[4][4];
#pragma unroll
    for (int i = 0; i < 4; ++i)
#pragma unroll
        for (int j = 0; j < 4; ++j) acc[i][j] = (f32x4){0.f, 0.f, 0.f, 0.f};

    g2lds16(gA0, &As[0][wv * 512]);
    g2lds16(gA1, &As[0][wv * 512 + 2048]);
    g2lds16(gB0, &Bs[0][wv * 512]);
    g2lds16(gB1, &Bs[0][wv * 512 + 2048]);

#pragma unroll
    for (int kk = 0; kk < 12; ++kk) {
        const int cur = kk & 1;
        if (kk < 11) {
            const int nxt = cur ^ 1;
            g2lds16(gA0 + (kk + 1) * 32, &As[nxt][wv * 512]);
            g2lds16(gA1 + (kk + 1) * 32, &As[nxt][wv * 512 + 2048]);
            g2lds16(gB0 + (kk + 1) * 32, &Bs[nxt][wv * 512]);
            g2lds16(gB1 + (kk + 1) * 32, &Bs[nxt][wv * 512 + 2048]);
            WAITVM_BAR(4);
        } else {
            WAITVM_BAR(0);
        }
        bf16x8 af[4], bfv[4];
#pragma unroll
        for (int mt = 0; mt < 4; ++mt)
            af[mt] = *(const bf16x8*)&As[cur][(wm * 64 + mt * 16 + l15) * 32 + rc];
#pragma unroll
        for (int nt = 0; nt < 4; ++nt)
            bfv[nt] = *(const bf16x8*)&Bs[cur][(wn * 64 + nt * 16 + l15) * 32 + rc];
#pragma unroll
        for (int mt = 0; mt < 4; ++mt)
#pragma unroll
            for (int nt = 0; nt < 4; ++nt)
                acc[mt][nt] = __builtin_amdgcn_mfma_f32_16x16x32_bf16(af[mt], bfv[nt], acc[mt][nt], 0, 0, 0);
        BAR();
    }
#pragma unroll
    for (int nt = 0; nt < 4; ++nt) {
        int col = col0 + wn * 64 + nt * 16 + l15;
        float bias = proj_bias[col];
#pragma unroll
        for (int mt = 0; mt < 4; ++mt) {
#pragma unroll
            for (int rr = 0; rr < 4; ++rr) {
                int row = row0 + wm * 64 + mt * 16 + g * 4 + rr;
                out[row_to_pixel(row) * CCH + col] = acc[mt][nt][rr] + bias;
            }
        }
    }
}

extern "C" void kernel_launch(void* const* d_in, const int* in_sizes, int n_in,
                              void* d_out, int out_size, void* d_ws, size_t ws_size,
                              hipStream_t stream) {
    const float* x     = (const float*)d_in[0];
    const float* qkvw  = (const float*)d_in[1];
    const float* qkvb  = (const float*)d_in[2];
    const float* projw = (const float*)d_in[3];
    const float* projb = (const float*)d_in[4];
    const float* rel   = (const float*)d_in[5];
    float* out = (float*)d_out;

    char* ws = (char*)d_ws;
    unsigned short* wqb = (unsigned short*)(ws);                       // 884736 B
    unsigned short* wpb = (unsigned short*)(ws + 884736);              // 294912 B
    float* btt2         = (float*)(ws + 884736 + 294912);              // 786432 B
    const size_t off  = 2097152;                                       // aligned past tables
    const size_t bufb = 38535168ull;                                   // 50176*384*2
    unsigned short* qb  = (unsigned short*)(ws + off);
    unsigned short* kb  = (unsigned short*)(ws + off + bufb);
    unsigned short* vb  = (unsigned short*)(ws + off + 2 * bufb);
    unsigned short* ao  = (unsigned short*)(ws + off + 3 * bufb);

    prep_kernel<<<1728, 256, 0, stream>>>(qkvw, projw, rel, wqb, wpb, btt2);
    qkv_gemm<<<1764, 512, 0, stream>>>(x, wqb, qkvb, qb, kb, vb);      // gather fused into A-staging
    attn_kernel<<<3072, 256, 0, stream>>>(qb, kb, vb, btt2, ao);
    proj_gemm<<<dim3(392, 3), 256, 0, stream>>>(ao, wpb, projb, out);
}

// Round 4
// 189.542 us; speedup vs baseline: 1.2587x; 1.2587x over previous
//
#include <hip/hip_runtime.h>

#define CCH 384
#define NHEADS 12
#define HDIM 32
#define NTOK 49
#define NWIN 1024
#define MROWS 50176
#define PSTR 72   // padded LDS stride for P tile (attn)

typedef __attribute__((ext_vector_type(8))) short bf16x8;
typedef __attribute__((ext_vector_type(4))) float f32x4;

#define WAITVM_BAR(N) asm volatile("s_waitcnt vmcnt(" #N ")\n\ts_barrier" ::: "memory")
#define BAR() asm volatile("s_barrier" ::: "memory")

__device__ __forceinline__ unsigned short f2bf(float f) {
    unsigned u = __builtin_bit_cast(unsigned, f);
    u += 0x7FFFu + ((u >> 16) & 1u);
    return (unsigned short)(u >> 16);
}

// async global -> LDS, 16B per lane. lds base must be wave-uniform.
__device__ __forceinline__ void g2lds16(const unsigned short* g, unsigned short* l) {
    __builtin_amdgcn_global_load_lds(
        (const __attribute__((address_space(1))) unsigned int*)g,
        (__attribute__((address_space(3))) unsigned int*)l,
        16, 0, 0);
}

// ---------------- prep: weights -> bf16, fused bias+mask table ----------------
__global__ void prep_kernel(const float* __restrict__ qkvw, const float* __restrict__ projw,
                            const float* __restrict__ rel_table,
                            unsigned short* __restrict__ wq, unsigned short* __restrict__ wp,
                            float* __restrict__ btt2) {
    int i = blockIdx.x * 256 + threadIdx.x;
    if (i < 3 * CCH * CCH) wq[i] = f2bf(qkvw[i]);
    if (i < CCH * CCH) wp[i] = f2bf(projw[i]);
    if (i < 4 * NHEADS * 16 * 64) {            // one float4 entry per thread
        int cls = i / (NHEADS * 16 * 64);
        int rem = i - cls * (NHEADS * 16 * 64);
        int h = rem / (16 * 64);
        int rem2 = rem - h * (16 * 64);
        int rb = rem2 >> 6, cj = rem2 & 63;
        int jreg = 0;
        if (cj < NTOK) {
            int jy = cj / 7, jx = cj - jy * 7;
            int ry = (cls & 2) ? ((jy < 4) ? 1 : 2) : 0;
            int rx = (cls & 1) ? ((jx < 4) ? 1 : 2) : 0;
            jreg = ry * 3 + rx;
        }
        float4 o;
        float* po = (float*)&o;
#pragma unroll
        for (int rr = 0; rr < 4; ++rr) {
            int ri = rb * 4 + rr;
            float v = -1e30f;
            if (ri < NTOK && cj < NTOK) {
                int iy = ri / 7, ix = ri - iy * 7;
                int jy = cj / 7, jx = cj - jy * 7;
                int idx = (iy - jy + 6) * 13 + (ix - jx + 6);
                v = rel_table[idx * NHEADS + h];
                int ry = (cls & 2) ? ((iy < 4) ? 1 : 2) : 0;
                int rx = (cls & 1) ? ((ix < 4) ? 1 : 2) : 0;
                if (ry * 3 + rx != jreg) v -= 100.f;
            }
            po[rr] = v;
        }
        *(float4*)&btt2[(size_t)i * 4] = o;
    }
}

// row -> source/dest pixel (roll by shift=3 folded in; same map both directions)
__device__ __forceinline__ size_t row_to_pixel(int r) {
    int wlin = r / 49, n = r - wlin * 49;
    int b = wlin >> 6, wimg = wlin & 63;
    int wy = wimg >> 3, wx = wimg & 7;
    int iy = n / 7, ix = n - iy * 7;
    int y = wy * 7 + iy + 3; if (y >= 56) y -= 56;
    int x = wx * 7 + ix + 3; if (x >= 56) x -= 56;
    return (size_t)((b * 56 + y) * 56 + x);
}

// ---------------- gather: x fp32 -> windowed/rolled bf16 panel ----------------
__global__ __launch_bounds__(256) void gather_kernel(const float* __restrict__ xin,
                                                     unsigned short* __restrict__ xw) {
    int idx = blockIdx.x * 256 + threadIdx.x;   // one float4 per thread
    int row = idx / 96, c4 = (idx - row * 96) * 4;
    const float4 v = *(const float4*)(xin + row_to_pixel(row) * CCH + c4);
    ushort4 o;
    o.x = f2bf(v.x); o.y = f2bf(v.y); o.z = f2bf(v.z); o.w = f2bf(v.w);
    *(ushort4*)(xw + (size_t)row * CCH + c4) = o;
}

// ---------------- QKV GEMM: 256x128 tile, BK=64, 8-phase-style schedule (T3+T4+T5),
// counted vmcnt at tile boundary only; chunk-XOR swizzle (f=row&7) both-sides ----------------
__global__ __launch_bounds__(512) void qkv_gemm(const unsigned short* __restrict__ xw,
        const unsigned short* __restrict__ wq, const float* __restrict__ qkv_bias,
        unsigned short* __restrict__ qb, unsigned short* __restrict__ kb,
        unsigned short* __restrict__ vb) {
    __shared__ unsigned short As[2][256 * 64];   // 2 x 32 KB
    __shared__ unsigned short Bs[2][128 * 64];   // 2 x 16 KB
    const int tid = threadIdx.x;
    // bijective XCD-chunk remap: nwg=1764, q=220, r=4 (m204 variant), col-fastest
    const int bid = blockIdx.x;
    const int xcd = bid & 7;
    const int base = (xcd < 4) ? xcd * 221 : (4 * 221 + (xcd - 4) * 220);
    const int swz = base + (bid >> 3);
    const int rbk = swz / 9, cbk = swz - rbk * 9;
    const int row0 = rbk * 256;
    const int col0 = cbk * 128;
    const int lane = tid & 63, wv = tid >> 6;   // 8 waves
    const int wm = wv >> 1, wn = wv & 1;        // 4M x 2N, wave tile 64x64
    const int l15 = lane & 15, g = lane >> 4;

    // ---- staging geometry: per K-tile (BK=64) per wave: A = 32 rows (4 loads x 8 rows),
    // B = 16 rows (2 loads). Lane covers chunk c=lane&7 of row base+(lane>>3).
    // Swizzle f(row)=row&7: LDS[r][c] holds global chunk c^ (r&7) (pre-swizzled source).
    const int lr8 = lane >> 3;                  // 0..7 row-in-group
    const int lc8 = lane & 7;                   // 16B chunk in 128B row
    const unsigned short* gA = xw + (size_t)(row0 + wv * 32 + lr8) * CCH + ((lc8 ^ lr8) * 8);
    const unsigned short* gB = wq + (size_t)(col0 + wv * 16 + lr8) * CCH + ((lc8 ^ lr8) * 8);

    // ---- fragment-read geometry: row r = {wm|wn}*64 + mt*16 + l15 -> f = l15&7.
    // chunk(ks) = (ks*4 + g) ^ f ; byte = chunk*16.
    const int aro = (wm * 64 + l15) * 64;
    const int bro = (wn * 64 + l15) * 64;
    const int cf = g ^ (l15 & 7);
    const int c0s = cf * 8;                     // ks=0 chunk (short offset)
    const int c1s = (cf ^ 4) * 8;               // ks=1 chunk

    f32x4 acc[4][4];
#pragma unroll
    for (int i = 0; i < 4; ++i)
#pragma unroll
        for (int j = 0; j < 4; ++j) acc[i][j] = (f32x4){0.f, 0.f, 0.f, 0.f};

    // ---- prologue: stage K-tile 0 into buffer 0 (6 DMA), drain, sync
    g2lds16(gA,            &As[0][(wv * 32 + 0) * 64]);
    g2lds16(gA + 3072,     &As[0][(wv * 32 + 8) * 64]);
    g2lds16(gA + 2 * 3072, &As[0][(wv * 32 + 16) * 64]);
    g2lds16(gA + 3 * 3072, &As[0][(wv * 32 + 24) * 64]);
    g2lds16(gB,            &Bs[0][(wv * 16 + 0) * 64]);
    g2lds16(gB + 3072,     &Bs[0][(wv * 16 + 8) * 64]);
    WAITVM_BAR(0);

#pragma unroll
    for (int t = 0; t < 6; ++t) {
        const int bcur = t & 1;
        const unsigned short* Ab = &As[bcur][0];
        const unsigned short* Bb = &Bs[bcur][0];
        unsigned short* An = &As[bcur ^ 1][0];
        unsigned short* Bn = &Bs[bcur ^ 1][0];
        const int tn = t + 1;
        bf16x8 af0, af1, af2, af3, bv0, bv1;

        // ===== phase 0: issue A0,A1(t+1); tile-t visibility (vmcnt counts the 2 new); ks0 x nt{0,1}
        if (t < 5) {
            g2lds16(gA + tn * 64,        An + (wv * 32 + 0) * 64);
            g2lds16(gA + tn * 64 + 3072, An + (wv * 32 + 8) * 64);
            WAITVM_BAR(2);   // tile t's 6 DMAs done (2 newest stay in flight)
        } else {
            WAITVM_BAR(0);
        }
        af0 = *(const bf16x8*)&Ab[aro + 0 * 1024 + c0s];
        af1 = *(const bf16x8*)&Ab[aro + 1 * 1024 + c0s];
        af2 = *(const bf16x8*)&Ab[aro + 2 * 1024 + c0s];
        af3 = *(const bf16x8*)&Ab[aro + 3 * 1024 + c0s];
        bv0 = *(const bf16x8*)&Bb[bro + 0 * 1024 + c0s];
        bv1 = *(const bf16x8*)&Bb[bro + 1 * 1024 + c0s];
        __builtin_amdgcn_s_setprio(1);
        acc[0][0] = __builtin_amdgcn_mfma_f32_16x16x32_bf16(af0, bv0, acc[0][0], 0, 0, 0);
        acc[1][0] = __builtin_amdgcn_mfma_f32_16x16x32_bf16(af1, bv0, acc[1][0], 0, 0, 0);
        acc[2][0] = __builtin_amdgcn_mfma_f32_16x16x32_bf16(af2, bv0, acc[2][0], 0, 0, 0);
        acc[3][0] = __builtin_amdgcn_mfma_f32_16x16x32_bf16(af3, bv0, acc[3][0], 0, 0, 0);
        acc[0][1] = __builtin_amdgcn_mfma_f32_16x16x32_bf16(af0, bv1, acc[0][1], 0, 0, 0);
        acc[1][1] = __builtin_amdgcn_mfma_f32_16x16x32_bf16(af1, bv1, acc[1][1], 0, 0, 0);
        acc[2][1] = __builtin_amdgcn_mfma_f32_16x16x32_bf16(af2, bv1, acc[2][1], 0, 0, 0);
        acc[3][1] = __builtin_amdgcn_mfma_f32_16x16x32_bf16(af3, bv1, acc[3][1], 0, 0, 0);
        __builtin_amdgcn_s_setprio(0);
        BAR();

        // ===== phase 1: issue A2,A3(t+1); ks0 x nt{2,3} (af reused)
        if (t < 5) {
            g2lds16(gA + tn * 64 + 2 * 3072, An + (wv * 32 + 16) * 64);
            g2lds16(gA + tn * 64 + 3 * 3072, An + (wv * 32 + 24) * 64);
        }
        bv0 = *(const bf16x8*)&Bb[bro + 2 * 1024 + c0s];
        bv1 = *(const bf16x8*)&Bb[bro + 3 * 1024 + c0s];
        __builtin_amdgcn_s_setprio(1);
        acc[0][2] = __builtin_amdgcn_mfma_f32_16x16x32_bf16(af0, bv0, acc[0][2], 0, 0, 0);
        acc[1][2] = __builtin_amdgcn_mfma_f32_16x16x32_bf16(af1, bv0, acc[1][2], 0, 0, 0);
        acc[2][2] = __builtin_amdgcn_mfma_f32_16x16x32_bf16(af2, bv0, acc[2][2], 0, 0, 0);
        acc[3][2] = __builtin_amdgcn_mfma_f32_16x16x32_bf16(af3, bv0, acc[3][2], 0, 0, 0);
        acc[0][3] = __builtin_amdgcn_mfma_f32_16x16x32_bf16(af0, bv1, acc[0][3], 0, 0, 0);
        acc[1][3] = __builtin_amdgcn_mfma_f32_16x16x32_bf16(af1, bv1, acc[1][3], 0, 0, 0);
        acc[2][3] = __builtin_amdgcn_mfma_f32_16x16x32_bf16(af2, bv1, acc[2][3], 0, 0, 0);
        acc[3][3] = __builtin_amdgcn_mfma_f32_16x16x32_bf16(af3, bv1, acc[3][3], 0, 0, 0);
        __builtin_amdgcn_s_setprio(0);
        BAR();

        // ===== phase 2: issue B0,B1(t+1); ks1 x nt{0,1}
        if (t < 5) {
            g2lds16(gB + tn * 64,        Bn + (wv * 16 + 0) * 64);
            g2lds16(gB + tn * 64 + 3072, Bn + (wv * 16 + 8) * 64);
        }
        af0 = *(const bf16x8*)&Ab[aro + 0 * 1024 + c1s];
        af1 = *(const bf16x8*)&Ab[aro + 1 * 1024 + c1s];
        af2 = *(const bf16x8*)&Ab[aro + 2 * 1024 + c1s];
        af3 = *(const bf16x8*)&Ab[aro + 3 * 1024 + c1s];
        bv0 = *(const bf16x8*)&Bb[bro + 0 * 1024 + c1s];
        bv1 = *(const bf16x8*)&Bb[bro + 1 * 1024 + c1s];
        __builtin_amdgcn_s_setprio(1);
        acc[0][0] = __builtin_amdgcn_mfma_f32_16x16x32_bf16(af0, bv0, acc[0][0], 0, 0, 0);
        acc[1][0] = __builtin_amdgcn_mfma_f32_16x16x32_bf16(af1, bv0, acc[1][0], 0, 0, 0);
        acc[2][0] = __builtin_amdgcn_mfma_f32_16x16x32_bf16(af2, bv0, acc[2][0], 0, 0, 0);
        acc[3][0] = __builtin_amdgcn_mfma_f32_16x16x32_bf16(af3, bv0, acc[3][0], 0, 0, 0);
        acc[0][1] = __builtin_amdgcn_mfma_f32_16x16x32_bf16(af0, bv1, acc[0][1], 0, 0, 0);
        acc[1][1] = __builtin_amdgcn_mfma_f32_16x16x32_bf16(af1, bv1, acc[1][1], 0, 0, 0);
        acc[2][1] = __builtin_amdgcn_mfma_f32_16x16x32_bf16(af2, bv1, acc[2][1], 0, 0, 0);
        acc[3][1] = __builtin_amdgcn_mfma_f32_16x16x32_bf16(af3, bv1, acc[3][1], 0, 0, 0);
        __builtin_amdgcn_s_setprio(0);
        BAR();

        // ===== phase 3: ks1 x nt{2,3}
        bv0 = *(const bf16x8*)&Bb[bro + 2 * 1024 + c1s];
        bv1 = *(const bf16x8*)&Bb[bro + 3 * 1024 + c1s];
        __builtin_amdgcn_s_setprio(1);
        acc[0][2] = __builtin_amdgcn_mfma_f32_16x16x32_bf16(af0, bv0, acc[0][2], 0, 0, 0);
        acc[1][2] = __builtin_amdgcn_mfma_f32_16x16x32_bf16(af1, bv0, acc[1][2], 0, 0, 0);
        acc[2][2] = __builtin_amdgcn_mfma_f32_16x16x32_bf16(af2, bv0, acc[2][2], 0, 0, 0);
        acc[3][2] = __builtin_amdgcn_mfma_f32_16x16x32_bf16(af3, bv0, acc[3][2], 0, 0, 0);
        acc[0][3] = __builtin_amdgcn_mfma_f32_16x16x32_bf16(af0, bv1, acc[0][3], 0, 0, 0);
        acc[1][3] = __builtin_amdgcn_mfma_f32_16x16x32_bf16(af1, bv1, acc[1][3], 0, 0, 0);
        acc[2][3] = __builtin_amdgcn_mfma_f32_16x16x32_bf16(af2, bv1, acc[2][3], 0, 0, 0);
        acc[3][3] = __builtin_amdgcn_mfma_f32_16x16x32_bf16(af3, bv1, acc[3][3], 0, 0, 0);
        __builtin_amdgcn_s_setprio(0);
        BAR();   // also the pre-issue safety barrier for next tile's phase-0 DMA
    }

    // epilogue (R7 form): + bias; q scaled; coalesced [inst][tok][dim]
    const float SCALE = 0.17677669529663687f;
#pragma unroll
    for (int nt = 0; nt < 4; ++nt) {
        int col = col0 + wn * 64 + nt * 16 + l15;
        float bias = qkv_bias[col];
        int which = col / CCH;
        int rem = col - which * CCH;
        int h = rem >> 5, d = rem & 31;
        unsigned short* dstb = (which == 0) ? qb : ((which == 1) ? kb : vb);
        float scl = (which == 0) ? SCALE : 1.0f;
#pragma unroll
        for (int mt = 0; mt < 4; ++mt) {
#pragma unroll
            for (int rr = 0; rr < 4; ++rr) {
                int row = row0 + wm * 64 + mt * 16 + g * 4 + rr;
                int w2 = row / 49, n2 = row - w2 * 49;
                size_t inst = (size_t)(w2 * NHEADS + h);
                float v = (acc[mt][nt][rr] + bias) * scl;
                dstb[(inst * NTOK + n2) * HDIM + d] = f2bf(v);
            }
        }
    }
}

// ---------------- attention: one wave per (window, head); V via swizzled LDS ----------------
__global__ __launch_bounds__(256) void attn_kernel(const unsigned short* __restrict__ qbuf,
        const unsigned short* __restrict__ kbuf, const unsigned short* __restrict__ vbuf,
        const float* __restrict__ btt2, unsigned short* __restrict__ ao) {
    __shared__ unsigned short Ps[4][64 * PSTR];
    __shared__ unsigned short Vt[4][32 * 64];   // [d][tok] with XOR-swizzled tok
    const int tid = threadIdx.x;
    const int lane = tid & 63, wv = tid >> 6;
    const int inst = blockIdx.x * 4 + wv;
    const int w = inst / NHEADS, h = inst - w * NHEADS;
    const int l15 = lane & 15, g = lane >> 4;
    const unsigned short* qp = qbuf + (size_t)inst * (NTOK * HDIM);
    const unsigned short* kp = kbuf + (size_t)inst * (NTOK * HDIM);
    const unsigned short* vp = vbuf + (size_t)inst * (NTOK * HDIM);

    const bf16x8 zero8 = {0, 0, 0, 0, 0, 0, 0, 0};
    // early V prefetch (T14): 4x16B; masked zero for tok>=49 (NaN-safe)
    bf16x8 vpre[4];
#pragma unroll
    for (int p = 0; p < 4; ++p) {
        int e0 = (p * 64 + lane) * 8;           // 8 elems share one tok (e0 8-aligned)
        int tok = e0 >> 5;
        vpre[p] = (tok < NTOK) ? *(const bf16x8*)&vp[e0] : zero8;
    }

    bf16x8 aq[4], bk[4];
#pragma unroll
    for (int mt = 0; mt < 4; ++mt) {
        int row = mt * 16 + l15;
        aq[mt] = (row < NTOK) ? *(const bf16x8*)&qp[row * HDIM + g * 8] : zero8;
    }
#pragma unroll
    for (int nt = 0; nt < 4; ++nt) {
        int colk = nt * 16 + l15;
        bk[nt] = (colk < NTOK) ? *(const bf16x8*)&kp[colk * HDIM + g * 8] : zero8;
    }
    f32x4 s[4][4];
#pragma unroll
    for (int mt = 0; mt < 4; ++mt)
#pragma unroll
        for (int nt = 0; nt < 4; ++nt)
            s[mt][nt] = __builtin_amdgcn_mfma_f32_16x16x32_bf16(aq[mt], bk[nt], (f32x4){0.f, 0.f, 0.f, 0.f}, 0, 0, 0);

    // write V to swizzled LDS transpose while QK^T/softmax proceed
    {
        unsigned short* vt = Vt[wv];
#pragma unroll
        for (int p = 0; p < 4; ++p) {
            int e0 = (p * 64 + lane) * 8;
            int tok = e0 >> 5, d0 = e0 & 31;
#pragma unroll
            for (int j = 0; j < 8; ++j) {
                int d = d0 + j;
                vt[d * 64 + (tok ^ ((d & 7) << 3))] = (unsigned short)vpre[p][j];
            }
        }
    }

    // logits: (pre-scaled q)K^T + fused bias/mask table; coalesced float4 loads
    const int wimg = w & 63;
    const int wy = wimg >> 3, wx = wimg & 7;
    const int wcls = (((wy == 7) ? 2 : 0) | ((wx == 7) ? 1 : 0));
    const float4* bt4 = (const float4*)btt2 + ((size_t)(wcls * NHEADS + h)) * (16 * 64);

    float inv[4][4];
#pragma unroll
    for (int mt = 0; mt < 4; ++mt) {
        float4 bias4[4];
#pragma unroll
        for (int nt = 0; nt < 4; ++nt)
            bias4[nt] = bt4[(mt * 4 + g) * 64 + nt * 16 + l15];
#pragma unroll
        for (int rr = 0; rr < 4; ++rr) {
#pragma unroll
            for (int nt = 0; nt < 4; ++nt) {
                float bb = (rr == 0) ? bias4[nt].x : (rr == 1) ? bias4[nt].y : (rr == 2) ? bias4[nt].z : bias4[nt].w;
                s[mt][nt][rr] += bb;
            }
            // row softmax (16-lane butterfly)
            float m = fmaxf(fmaxf(s[mt][0][rr], s[mt][1][rr]), fmaxf(s[mt][2][rr], s[mt][3][rr]));
            m = fmaxf(m, __shfl_xor(m, 1));
            m = fmaxf(m, __shfl_xor(m, 2));
            m = fmaxf(m, __shfl_xor(m, 4));
            m = fmaxf(m, __shfl_xor(m, 8));
            float sum = 0.f;
#pragma unroll
            for (int nt = 0; nt < 4; ++nt) {
                float p = __expf(s[mt][nt][rr] - m);
                s[mt][nt][rr] = p;
                sum += p;
            }
            sum += __shfl_xor(sum, 1);
            sum += __shfl_xor(sum, 2);
            sum += __shfl_xor(sum, 4);
            sum += __shfl_xor(sum, 8);
            inv[mt][rr] = 1.0f / sum;
        }
    }
    // P -> LDS (re-fragment for PV)
    unsigned short* ps = Ps[wv];
#pragma unroll
    for (int mt = 0; mt < 4; ++mt)
#pragma unroll
        for (int nt = 0; nt < 4; ++nt)
#pragma unroll
            for (int rr = 0; rr < 4; ++rr)
                ps[(mt * 16 + g * 4 + rr) * PSTR + nt * 16 + l15] = f2bf(s[mt][nt][rr]);

    f32x4 o[4][2];
#pragma unroll
    for (int mt = 0; mt < 4; ++mt)
#pragma unroll
        for (int dt = 0; dt < 2; ++dt) o[mt][dt] = (f32x4){0.f, 0.f, 0.f, 0.f};

    const unsigned short* vt = Vt[wv];
#pragma unroll
    for (int kt = 0; kt < 2; ++kt) {
        bf16x8 ap[4];
#pragma unroll
        for (int mt = 0; mt < 4; ++mt)
            ap[mt] = *(const bf16x8*)&ps[(mt * 16 + l15) * PSTR + kt * 32 + g * 8];
#pragma unroll
        for (int dt = 0; dt < 2; ++dt) {
            const int d = dt * 16 + l15;
            const int cb = kt * 32 + g * 8;
            bf16x8 bv = *(const bf16x8*)&vt[d * 64 + (cb ^ ((d & 7) << 3))];
#pragma unroll
            for (int mt = 0; mt < 4; ++mt)
                o[mt][dt] = __builtin_amdgcn_mfma_f32_16x16x32_bf16(ap[mt], bv, o[mt][dt], 0, 0, 0);
        }
    }
    // write attn-out [M=50176][384] bf16
#pragma unroll
    for (int mt = 0; mt < 4; ++mt)
#pragma unroll
        for (int dt = 0; dt < 2; ++dt)
#pragma unroll
            for (int rr = 0; rr < 4; ++rr) {
                int row = mt * 16 + g * 4 + rr;
                if (row < NTOK) {
                    float val = o[mt][dt][rr] * inv[mt][rr];
                    ao[((size_t)(w * NTOK + row)) * CCH + h * HDIM + dt * 16 + l15] = f2bf(val);
                }
            }
}

// ---------------- proj GEMM: 128x128 tile, dbuf pipeline, fused scatter,
// bank-conflict swizzle via pre-swizzled g2lds16 source + swizzled reads ----------------
__global__ __launch_bounds__(256) void proj_gemm(const unsigned short* __restrict__ ain,
        const unsigned short* __restrict__ wp, const float* __restrict__ proj_bias,
        float* __restrict__ out) {
    __shared__ unsigned short As[2][128 * 32];
    __shared__ unsigned short Bs[2][128 * 32];
    const int tid = threadIdx.x;
    const int row0 = blockIdx.x * 128;
    const int col0 = blockIdx.y * 128;
    const int lane = tid & 63, wv = tid >> 6;
    const int wm = wv >> 1, wn = wv & 1;
    const int l15 = lane & 15, g = lane >> 4;

    const int srow = wv * 16 + (lane >> 2);               // group1 = +64, same f
    const int scs = (((lane & 3) ^ ((srow >> 1) & 3)) * 8);   // pre-swizzled source chunk
    const unsigned short* gA0 = ain + (size_t)(row0 + srow) * CCH + scs;
    const unsigned short* gA1 = gA0 + (size_t)64 * CCH;
    const unsigned short* gB0 = wp + (size_t)(col0 + srow) * CCH + scs;
    const unsigned short* gB1 = gB0 + (size_t)64 * CCH;
    const int rc = (g ^ ((l15 >> 1) & 3)) * 8;            // swizzled fragment-read chunk

    f32x4 acc[4][4];
#pragma unroll
    for (int i = 0; i < 4; ++i)
#pragma unroll
        for (int j = 0; j < 4; ++j) acc[i][j] = (f32x4){0.f, 0.f, 0.f, 0.f};

    g2lds16(gA0, &As[0][wv * 512]);
    g2lds16(gA1, &As[0][wv * 512 + 2048]);
    g2lds16(gB0, &Bs[0][wv * 512]);
    g2lds16(gB1, &Bs[0][wv * 512 + 2048]);

#pragma unroll
    for (int kk = 0; kk < 12; ++kk) {
        const int cur = kk & 1;
        if (kk < 11) {
            const int nxt = cur ^ 1;
            g2lds16(gA0 + (kk + 1) * 32, &As[nxt][wv * 512]);
            g2lds16(gA1 + (kk + 1) * 32, &As[nxt][wv * 512 + 2048]);
            g2lds16(gB0 + (kk + 1) * 32, &Bs[nxt][wv * 512]);
            g2lds16(gB1 + (kk + 1) * 32, &Bs[nxt][wv * 512 + 2048]);
            WAITVM_BAR(4);
        } else {
            WAITVM_BAR(0);
        }
        bf16x8 af[4], bfv[4];
#pragma unroll
        for (int mt = 0; mt < 4; ++mt)
            af[mt] = *(const bf16x8*)&As[cur][(wm * 64 + mt * 16 + l15) * 32 + rc];
#pragma unroll
        for (int nt = 0; nt < 4; ++nt)
            bfv[nt] = *(const bf16x8*)&Bs[cur][(wn * 64 + nt * 16 + l15) * 32 + rc];
#pragma unroll
        for (int mt = 0; mt < 4; ++mt)
#pragma unroll
            for (int nt = 0; nt < 4; ++nt)
                acc[mt][nt] = __builtin_amdgcn_mfma_f32_16x16x32_bf16(af[mt], bfv[nt], acc[mt][nt], 0, 0, 0);
        BAR();
    }
#pragma unroll
    for (int nt = 0; nt < 4; ++nt) {
        int col = col0 + wn * 64 + nt * 16 + l15;
        float bias = proj_bias[col];
#pragma unroll
        for (int mt = 0; mt < 4; ++mt) {
#pragma unroll
            for (int rr = 0; rr < 4; ++rr) {
                int row = row0 + wm * 64 + mt * 16 + g * 4 + rr;
                out[row_to_pixel(row) * CCH + col] = acc[mt][nt][rr] + bias;
            }
        }
    }
}

extern "C" void kernel_launch(void* const* d_in, const int* in_sizes, int n_in,
                              void* d_out, int out_size, void* d_ws, size_t ws_size,
                              hipStream_t stream) {
    const float* x     = (const float*)d_in[0];
    const float* qkvw  = (const float*)d_in[1];
    const float* qkvb  = (const float*)d_in[2];
    const float* projw = (const float*)d_in[3];
    const float* projb = (const float*)d_in[4];
    const float* rel   = (const float*)d_in[5];
    float* out = (float*)d_out;

    char* ws = (char*)d_ws;
    unsigned short* wqb = (unsigned short*)(ws);                       // 884736 B
    unsigned short* wpb = (unsigned short*)(ws + 884736);              // 294912 B
    float* btt2         = (float*)(ws + 884736 + 294912);              // 786432 B
    const size_t off  = 2097152;                                       // aligned past tables
    const size_t bufb = 38535168ull;                                   // 50176*384*2
    unsigned short* qb  = (unsigned short*)(ws + off);
    unsigned short* kb  = (unsigned short*)(ws + off + bufb);
    unsigned short* vb  = (unsigned short*)(ws + off + 2 * bufb);
    unsigned short* ao  = (unsigned short*)(ws + off + 3 * bufb);
    unsigned short* xw  = ao;   // alias: xw dead once qkv_gemm finishes, before attn writes ao

    prep_kernel<<<1728, 256, 0, stream>>>(qkvw, projw, rel, wqb, wpb, btt2);
    gather_kernel<<<18816, 256, 0, stream>>>(x, xw);
    qkv_gemm<<<1764, 512, 0, stream>>>(xw, wqb, qkvb, qb, kb, vb);
    attn_kernel<<<3072, 256, 0, stream>>>(qb, kb, vb, btt2, ao);
    proj_gemm<<<dim3(392, 3), 256, 0, stream>>>(ao, wpb, projb, out);
}

// Round 5
// 175.571 us; speedup vs baseline: 1.3588x; 1.0796x over previous
//
#include <hip/hip_runtime.h>

#define CCH 384
#define NHEADS 12
#define HDIM 32
#define NTOK 49
#define NWIN 1024
#define MROWS 50176
#define PSTR 72   // padded LDS stride for P tile (attn)

typedef __attribute__((ext_vector_type(8))) short bf16x8;
typedef __attribute__((ext_vector_type(4))) float f32x4;

#define WAITVM_BAR(N) asm volatile("s_waitcnt vmcnt(" #N ")\n\ts_barrier" ::: "memory")
#define BAR() asm volatile("s_barrier" ::: "memory")

__device__ __forceinline__ unsigned short f2bf(float f) {
    unsigned u = __builtin_bit_cast(unsigned, f);
    u += 0x7FFFu + ((u >> 16) & 1u);
    return (unsigned short)(u >> 16);
}

// async global -> LDS, 16B per lane. lds base must be wave-uniform.
__device__ __forceinline__ void g2lds16(const unsigned short* g, unsigned short* l) {
    __builtin_amdgcn_global_load_lds(
        (const __attribute__((address_space(1))) unsigned int*)g,
        (__attribute__((address_space(3))) unsigned int*)l,
        16, 0, 0);
}

// row -> source/dest pixel (roll by shift=3 folded in; same map both directions)
__device__ __forceinline__ size_t row_to_pixel(int r) {
    int wlin = r / 49, n = r - wlin * 49;
    int b = wlin >> 6, wimg = wlin & 63;
    int wy = wimg >> 3, wx = wimg & 7;
    int iy = n / 7, ix = n - iy * 7;
    int y = wy * 7 + iy + 3; if (y >= 56) y -= 56;
    int x = wx * 7 + ix + 3; if (x >= 56) x -= 56;
    return (size_t)((b * 56 + y) * 56 + x);
}

// ---------------- fused prep+gather: disjoint block ranges (independent outputs) ----------------
// blocks [0, 18816): gather x fp32 -> windowed/rolled bf16 panel
// blocks [18816, 20544): weights -> bf16, fused bias+mask table
__global__ __launch_bounds__(256) void prep_gather(const float* __restrict__ xin,
                            unsigned short* __restrict__ xw,
                            const float* __restrict__ qkvw, const float* __restrict__ projw,
                            const float* __restrict__ rel_table,
                            unsigned short* __restrict__ wq, unsigned short* __restrict__ wp,
                            float* __restrict__ btt2) {
    const int blk = blockIdx.x;
    if (blk < 18816) {
        int idx = blk * 256 + threadIdx.x;   // one float4 per thread
        int row = idx / 96, c4 = (idx - row * 96) * 4;
        const float4 v = *(const float4*)(xin + row_to_pixel(row) * CCH + c4);
        ushort4 o;
        o.x = f2bf(v.x); o.y = f2bf(v.y); o.z = f2bf(v.z); o.w = f2bf(v.w);
        *(ushort4*)(xw + (size_t)row * CCH + c4) = o;
        return;
    }
    int i = (blk - 18816) * 256 + threadIdx.x;
    if (i < 3 * CCH * CCH) wq[i] = f2bf(qkvw[i]);
    if (i < CCH * CCH) wp[i] = f2bf(projw[i]);
    if (i < 4 * NHEADS * 16 * 64) {            // one float4 entry per thread
        int cls = i / (NHEADS * 16 * 64);
        int rem = i - cls * (NHEADS * 16 * 64);
        int h = rem / (16 * 64);
        int rem2 = rem - h * (16 * 64);
        int rb = rem2 >> 6, cj = rem2 & 63;
        int jreg = 0;
        if (cj < NTOK) {
            int jy = cj / 7, jx = cj - jy * 7;
            int ry = (cls & 2) ? ((jy < 4) ? 1 : 2) : 0;
            int rx = (cls & 1) ? ((jx < 4) ? 1 : 2) : 0;
            jreg = ry * 3 + rx;
        }
        float4 o;
        float* po = (float*)&o;
#pragma unroll
        for (int rr = 0; rr < 4; ++rr) {
            int ri = rb * 4 + rr;
            float v = -1e30f;
            if (ri < NTOK && cj < NTOK) {
                int iy = ri / 7, ix = ri - iy * 7;
                int jy = cj / 7, jx = cj - jy * 7;
                int idx = (iy - jy + 6) * 13 + (ix - jx + 6);
                v = rel_table[idx * NHEADS + h];
                int ry = (cls & 2) ? ((iy < 4) ? 1 : 2) : 0;
                int rx = (cls & 1) ? ((ix < 4) ? 1 : 2) : 0;
                if (ry * 3 + rx != jreg) v -= 100.f;
            }
            po[rr] = v;
        }
        *(float4*)&btt2[(size_t)i * 4] = o;
    }
}

// ---------------- QKV GEMM: 128x128 tile (m92: 128^2 > 256^2 at this structure),
// 32KB LDS -> 5 blocks/CU TLP; dbuf g2lds16 pipeline; conflict-free chunk-XOR swizzle;
// bijective XCD swizzle (nwg=3528 = 8*441) ----------------
__global__ __launch_bounds__(256) void qkv_gemm(const unsigned short* __restrict__ xw,
        const unsigned short* __restrict__ wq, const float* __restrict__ qkv_bias,
        unsigned short* __restrict__ qb, unsigned short* __restrict__ kb,
        unsigned short* __restrict__ vb) {
    __shared__ unsigned short As[2][128 * 32];
    __shared__ unsigned short Bs[2][128 * 32];
    const int tid = threadIdx.x;
    const int bid = blockIdx.x;
    const int swz = (bid & 7) * 441 + (bid >> 3);   // 3528 % 8 == 0: exact bijection
    const int rb = swz / 9, cb = swz - rb * 9;      // col-fastest: 9 col-blocks share A panel in L2
    const int row0 = rb * 128;
    const int col0 = cb * 128;
    const int lane = tid & 63, wv = tid >> 6;       // 4 waves
    const int wm = wv >> 1, wn = wv & 1;            // 2M x 2N, wave tile 64x64
    const int l15 = lane & 15, g = lane >> 4;

    // staging: per wave 2 A-loads + 2 B-loads (16 rows each); f(row)=(row>>1)&3, f(r)==f(r+64)
    const int srow = wv * 16 + (lane >> 2);
    const int scs = (((lane & 3) ^ ((srow >> 1) & 3)) * 8);   // pre-swizzled source chunk
    const unsigned short* gA0 = xw + (size_t)(row0 + srow) * CCH + scs;
    const unsigned short* gA1 = gA0 + (size_t)64 * CCH;
    const unsigned short* gB0 = wq + (size_t)(col0 + srow) * CCH + scs;
    const unsigned short* gB1 = gB0 + (size_t)64 * CCH;
    const int rc = (g ^ ((l15 >> 1) & 3)) * 8;      // swizzled fragment-read chunk

    f32x4 acc[4][4];
#pragma unroll
    for (int i = 0; i < 4; ++i)
#pragma unroll
        for (int j = 0; j < 4; ++j) acc[i][j] = (f32x4){0.f, 0.f, 0.f, 0.f};

    g2lds16(gA0, &As[0][wv * 512]);
    g2lds16(gA1, &As[0][wv * 512 + 2048]);
    g2lds16(gB0, &Bs[0][wv * 512]);
    g2lds16(gB1, &Bs[0][wv * 512 + 2048]);

#pragma unroll
    for (int kk = 0; kk < 12; ++kk) {
        const int cur = kk & 1;
        if (kk < 11) {
            const int nxt = cur ^ 1;
            g2lds16(gA0 + (kk + 1) * 32, &As[nxt][wv * 512]);
            g2lds16(gA1 + (kk + 1) * 32, &As[nxt][wv * 512 + 2048]);
            g2lds16(gB0 + (kk + 1) * 32, &Bs[nxt][wv * 512]);
            g2lds16(gB1 + (kk + 1) * 32, &Bs[nxt][wv * 512 + 2048]);
            WAITVM_BAR(4);   // tile kk landed; next-tile loads stay in flight
        } else {
            WAITVM_BAR(0);
        }
        bf16x8 af[4], bfv[4];
#pragma unroll
        for (int mt = 0; mt < 4; ++mt)
            af[mt] = *(const bf16x8*)&As[cur][(wm * 64 + mt * 16 + l15) * 32 + rc];
#pragma unroll
        for (int nt = 0; nt < 4; ++nt)
            bfv[nt] = *(const bf16x8*)&Bs[cur][(wn * 64 + nt * 16 + l15) * 32 + rc];
#pragma unroll
        for (int mt = 0; mt < 4; ++mt)
#pragma unroll
            for (int nt = 0; nt < 4; ++nt)
                acc[mt][nt] = __builtin_amdgcn_mfma_f32_16x16x32_bf16(af[mt], bfv[nt], acc[mt][nt], 0, 0, 0);
        BAR();               // all waves done reading buf[cur] before overwrite
    }

    // epilogue (R7 form): + bias; q scaled; coalesced [inst][tok][dim]
    const float SCALE = 0.17677669529663687f;
#pragma unroll
    for (int nt = 0; nt < 4; ++nt) {
        int col = col0 + wn * 64 + nt * 16 + l15;
        float bias = qkv_bias[col];
        int which = col / CCH;
        int rem = col - which * CCH;
        int h = rem >> 5, d = rem & 31;
        unsigned short* dstb = (which == 0) ? qb : ((which == 1) ? kb : vb);
        float scl = (which == 0) ? SCALE : 1.0f;
#pragma unroll
        for (int mt = 0; mt < 4; ++mt) {
#pragma unroll
            for (int rr = 0; rr < 4; ++rr) {
                int row = row0 + wm * 64 + mt * 16 + g * 4 + rr;
                int w2 = row / 49, n2 = row - w2 * 49;
                size_t inst = (size_t)(w2 * NHEADS + h);
                float v = (acc[mt][nt][rr] + bias) * scl;
                dstb[(inst * NTOK + n2) * HDIM + d] = f2bf(v);
            }
        }
    }
}

// ---------------- attention: one wave per (window, head); V via swizzled LDS ----------------
__global__ __launch_bounds__(256) void attn_kernel(const unsigned short* __restrict__ qbuf,
        const unsigned short* __restrict__ kbuf, const unsigned short* __restrict__ vbuf,
        const float* __restrict__ btt2, unsigned short* __restrict__ ao) {
    __shared__ unsigned short Ps[4][64 * PSTR];
    __shared__ unsigned short Vt[4][32 * 64];   // [d][tok] with XOR-swizzled tok
    const int tid = threadIdx.x;
    const int lane = tid & 63, wv = tid >> 6;
    const int inst = blockIdx.x * 4 + wv;
    const int w = inst / NHEADS, h = inst - w * NHEADS;
    const int l15 = lane & 15, g = lane >> 4;
    const unsigned short* qp = qbuf + (size_t)inst * (NTOK * HDIM);
    const unsigned short* kp = kbuf + (size_t)inst * (NTOK * HDIM);
    const unsigned short* vp = vbuf + (size_t)inst * (NTOK * HDIM);

    const bf16x8 zero8 = {0, 0, 0, 0, 0, 0, 0, 0};
    // early V prefetch (T14): 4x16B; masked zero for tok>=49 (NaN-safe)
    bf16x8 vpre[4];
#pragma unroll
    for (int p = 0; p < 4; ++p) {
        int e0 = (p * 64 + lane) * 8;           // 8 elems share one tok (e0 8-aligned)
        int tok = e0 >> 5;
        vpre[p] = (tok < NTOK) ? *(const bf16x8*)&vp[e0] : zero8;
    }

    bf16x8 aq[4], bk[4];
#pragma unroll
    for (int mt = 0; mt < 4; ++mt) {
        int row = mt * 16 + l15;
        aq[mt] = (row < NTOK) ? *(const bf16x8*)&qp[row * HDIM + g * 8] : zero8;
    }
#pragma unroll
    for (int nt = 0; nt < 4; ++nt) {
        int colk = nt * 16 + l15;
        bk[nt] = (colk < NTOK) ? *(const bf16x8*)&kp[colk * HDIM + g * 8] : zero8;
    }
    f32x4 s[4][4];
#pragma unroll
    for (int mt = 0; mt < 4; ++mt)
#pragma unroll
        for (int nt = 0; nt < 4; ++nt)
            s[mt][nt] = __builtin_amdgcn_mfma_f32_16x16x32_bf16(aq[mt], bk[nt], (f32x4){0.f, 0.f, 0.f, 0.f}, 0, 0, 0);

    // write V to swizzled LDS transpose while QK^T/softmax proceed
    {
        unsigned short* vt = Vt[wv];
#pragma unroll
        for (int p = 0; p < 4; ++p) {
            int e0 = (p * 64 + lane) * 8;
            int tok = e0 >> 5, d0 = e0 & 31;
#pragma unroll
            for (int j = 0; j < 8; ++j) {
                int d = d0 + j;
                vt[d * 64 + (tok ^ ((d & 7) << 3))] = (unsigned short)vpre[p][j];
            }
        }
    }

    // logits: (pre-scaled q)K^T + fused bias/mask table; coalesced float4 loads
    const int wimg = w & 63;
    const int wy = wimg >> 3, wx = wimg & 7;
    const int wcls = (((wy == 7) ? 2 : 0) | ((wx == 7) ? 1 : 0));
    const float4* bt4 = (const float4*)btt2 + ((size_t)(wcls * NHEADS + h)) * (16 * 64);

    float inv[4][4];
#pragma unroll
    for (int mt = 0; mt < 4; ++mt) {
        float4 bias4[4];
#pragma unroll
        for (int nt = 0; nt < 4; ++nt)
            bias4[nt] = bt4[(mt * 4 + g) * 64 + nt * 16 + l15];
#pragma unroll
        for (int rr = 0; rr < 4; ++rr) {
#pragma unroll
            for (int nt = 0; nt < 4; ++nt) {
                float bb = (rr == 0) ? bias4[nt].x : (rr == 1) ? bias4[nt].y : (rr == 2) ? bias4[nt].z : bias4[nt].w;
                s[mt][nt][rr] += bb;
            }
            // row softmax (16-lane butterfly)
            float m = fmaxf(fmaxf(s[mt][0][rr], s[mt][1][rr]), fmaxf(s[mt][2][rr], s[mt][3][rr]));
            m = fmaxf(m, __shfl_xor(m, 1));
            m = fmaxf(m, __shfl_xor(m, 2));
            m = fmaxf(m, __shfl_xor(m, 4));
            m = fmaxf(m, __shfl_xor(m, 8));
            float sum = 0.f;
#pragma unroll
            for (int nt = 0; nt < 4; ++nt) {
                float p = __expf(s[mt][nt][rr] - m);
                s[mt][nt][rr] = p;
                sum += p;
            }
            sum += __shfl_xor(sum, 1);
            sum += __shfl_xor(sum, 2);
            sum += __shfl_xor(sum, 4);
            sum += __shfl_xor(sum, 8);
            inv[mt][rr] = 1.0f / sum;
        }
    }
    // P -> LDS (re-fragment for PV)
    unsigned short* ps = Ps[wv];
#pragma unroll
    for (int mt = 0; mt < 4; ++mt)
#pragma unroll
        for (int nt = 0; nt < 4; ++nt)
#pragma unroll
            for (int rr = 0; rr < 4; ++rr)
                ps[(mt * 16 + g * 4 + rr) * PSTR + nt * 16 + l15] = f2bf(s[mt][nt][rr]);

    f32x4 o[4][2];
#pragma unroll
    for (int mt = 0; mt < 4; ++mt)
#pragma unroll
        for (int dt = 0; dt < 2; ++dt) o[mt][dt] = (f32x4){0.f, 0.f, 0.f, 0.f};

    const unsigned short* vt = Vt[wv];
#pragma unroll
    for (int kt = 0; kt < 2; ++kt) {
        bf16x8 ap[4];
#pragma unroll
        for (int mt = 0; mt < 4; ++mt)
            ap[mt] = *(const bf16x8*)&ps[(mt * 16 + l15) * PSTR + kt * 32 + g * 8];
#pragma unroll
        for (int dt = 0; dt < 2; ++dt) {
            const int d = dt * 16 + l15;
            const int cb = kt * 32 + g * 8;
            bf16x8 bv = *(const bf16x8*)&vt[d * 64 + (cb ^ ((d & 7) << 3))];
#pragma unroll
            for (int mt = 0; mt < 4; ++mt)
                o[mt][dt] = __builtin_amdgcn_mfma_f32_16x16x32_bf16(ap[mt], bv, o[mt][dt], 0, 0, 0);
        }
    }
    // write attn-out [M=50176][384] bf16
#pragma unroll
    for (int mt = 0; mt < 4; ++mt)
#pragma unroll
        for (int dt = 0; dt < 2; ++dt)
#pragma unroll
            for (int rr = 0; rr < 4; ++rr) {
                int row = mt * 16 + g * 4 + rr;
                if (row < NTOK) {
                    float val = o[mt][dt][rr] * inv[mt][rr];
                    ao[((size_t)(w * NTOK + row)) * CCH + h * HDIM + dt * 16 + l15] = f2bf(val);
                }
            }
}

// ---------------- proj GEMM: 128x128 tile, dbuf pipeline, fused scatter,
// bank-conflict swizzle via pre-swizzled g2lds16 source + swizzled reads ----------------
__global__ __launch_bounds__(256) void proj_gemm(const unsigned short* __restrict__ ain,
        const unsigned short* __restrict__ wp, const float* __restrict__ proj_bias,
        float* __restrict__ out) {
    __shared__ unsigned short As[2][128 * 32];
    __shared__ unsigned short Bs[2][128 * 32];
    const int tid = threadIdx.x;
    const int row0 = blockIdx.x * 128;
    const int col0 = blockIdx.y * 128;
    const int lane = tid & 63, wv = tid >> 6;
    const int wm = wv >> 1, wn = wv & 1;
    const int l15 = lane & 15, g = lane >> 4;

    const int srow = wv * 16 + (lane >> 2);               // group1 = +64, same f
    const int scs = (((lane & 3) ^ ((srow >> 1) & 3)) * 8);   // pre-swizzled source chunk
    const unsigned short* gA0 = ain + (size_t)(row0 + srow) * CCH + scs;
    const unsigned short* gA1 = gA0 + (size_t)64 * CCH;
    const unsigned short* gB0 = wp + (size_t)(col0 + srow) * CCH + scs;
    const unsigned short* gB1 = gB0 + (size_t)64 * CCH;
    const int rc = (g ^ ((l15 >> 1) & 3)) * 8;            // swizzled fragment-read chunk

    f32x4 acc[4][4];
#pragma unroll
    for (int i = 0; i < 4; ++i)
#pragma unroll
        for (int j = 0; j < 4; ++j) acc[i][j] = (f32x4){0.f, 0.f, 0.f, 0.f};

    g2lds16(gA0, &As[0][wv * 512]);
    g2lds16(gA1, &As[0][wv * 512 + 2048]);
    g2lds16(gB0, &Bs[0][wv * 512]);
    g2lds16(gB1, &Bs[0][wv * 512 + 2048]);

#pragma unroll
    for (int kk = 0; kk < 12; ++kk) {
        const int cur = kk & 1;
        if (kk < 11) {
            const int nxt = cur ^ 1;
            g2lds16(gA0 + (kk + 1) * 32, &As[nxt][wv * 512]);
            g2lds16(gA1 + (kk + 1) * 32, &As[nxt][wv * 512 + 2048]);
            g2lds16(gB0 + (kk + 1) * 32, &Bs[nxt][wv * 512]);
            g2lds16(gB1 + (kk + 1) * 32, &Bs[nxt][wv * 512 + 2048]);
            WAITVM_BAR(4);
        } else {
            WAITVM_BAR(0);
        }
        bf16x8 af[4], bfv[4];
#pragma unroll
        for (int mt = 0; mt < 4; ++mt)
            af[mt] = *(const bf16x8*)&As[cur][(wm * 64 + mt * 16 + l15) * 32 + rc];
#pragma unroll
        for (int nt = 0; nt < 4; ++nt)
            bfv[nt] = *(const bf16x8*)&Bs[cur][(wn * 64 + nt * 16 + l15) * 32 + rc];
#pragma unroll
        for (int mt = 0; mt < 4; ++mt)
#pragma unroll
            for (int nt = 0; nt < 4; ++nt)
                acc[mt][nt] = __builtin_amdgcn_mfma_f32_16x16x32_bf16(af[mt], bfv[nt], acc[mt][nt], 0, 0, 0);
        BAR();
    }
#pragma unroll
    for (int nt = 0; nt < 4; ++nt) {
        int col = col0 + wn * 64 + nt * 16 + l15;
        float bias = proj_bias[col];
#pragma unroll
        for (int mt = 0; mt < 4; ++mt) {
#pragma unroll
            for (int rr = 0; rr < 4; ++rr) {
                int row = row0 + wm * 64 + mt * 16 + g * 4 + rr;
                out[row_to_pixel(row) * CCH + col] = acc[mt][nt][rr] + bias;
            }
        }
    }
}

extern "C" void kernel_launch(void* const* d_in, const int* in_sizes, int n_in,
                              void* d_out, int out_size, void* d_ws, size_t ws_size,
                              hipStream_t stream) {
    const float* x     = (const float*)d_in[0];
    const float* qkvw  = (const float*)d_in[1];
    const float* qkvb  = (const float*)d_in[2];
    const float* projw = (const float*)d_in[3];
    const float* projb = (const float*)d_in[4];
    const float* rel   = (const float*)d_in[5];
    float* out = (float*)d_out;

    char* ws = (char*)d_ws;
    unsigned short* wqb = (unsigned short*)(ws);                       // 884736 B
    unsigned short* wpb = (unsigned short*)(ws + 884736);              // 294912 B
    float* btt2         = (float*)(ws + 884736 + 294912);              // 786432 B
    const size_t off  = 2097152;                                       // aligned past tables
    const size_t bufb = 38535168ull;                                   // 50176*384*2
    unsigned short* qb  = (unsigned short*)(ws + off);
    unsigned short* kb  = (unsigned short*)(ws + off + bufb);
    unsigned short* vb  = (unsigned short*)(ws + off + 2 * bufb);
    unsigned short* ao  = (unsigned short*)(ws + off + 3 * bufb);
    unsigned short* xw  = ao;   // alias: xw dead once qkv_gemm finishes, before attn writes ao

    prep_gather<<<20544, 256, 0, stream>>>(x, xw, qkvw, projw, rel, wqb, wpb, btt2);
    qkv_gemm<<<3528, 256, 0, stream>>>(xw, wqb, qkvb, qb, kb, vb);
    attn_kernel<<<3072, 256, 0, stream>>>(qb, kb, vb, btt2, ao);
    proj_gemm<<<dim3(392, 3), 256, 0, stream>>>(ao, wpb, projb, out);
}

// Round 6
// 173.475 us; speedup vs baseline: 1.3752x; 1.0121x over previous
//
#include <hip/hip_runtime.h>

#define CCH 384
#define NHEADS 12
#define HDIM 32
#define NTOK 49
#define NWIN 1024
#define MROWS 50176
#define PSTR 72   // padded LDS stride for P tile (attn)

typedef __attribute__((ext_vector_type(8))) short bf16x8;
typedef __attribute__((ext_vector_type(4))) float f32x4;

#define WAITVM_BAR(N) asm volatile("s_waitcnt vmcnt(" #N ")\n\ts_barrier" ::: "memory")
#define BAR() asm volatile("s_barrier" ::: "memory")

__device__ __forceinline__ unsigned short f2bf(float f) {
    unsigned u = __builtin_bit_cast(unsigned, f);
    u += 0x7FFFu + ((u >> 16) & 1u);
    return (unsigned short)(u >> 16);
}

// async global -> LDS, 16B per lane. lds base must be wave-uniform.
__device__ __forceinline__ void g2lds16(const unsigned short* g, unsigned short* l) {
    __builtin_amdgcn_global_load_lds(
        (const __attribute__((address_space(1))) unsigned int*)g,
        (__attribute__((address_space(3))) unsigned int*)l,
        16, 0, 0);
}

// row -> source/dest pixel (roll by shift=3 folded in; same map both directions)
__device__ __forceinline__ size_t row_to_pixel(int r) {
    int wlin = r / 49, n = r - wlin * 49;
    int b = wlin >> 6, wimg = wlin & 63;
    int wy = wimg >> 3, wx = wimg & 7;
    int iy = n / 7, ix = n - iy * 7;
    int y = wy * 7 + iy + 3; if (y >= 56) y -= 56;
    int x = wx * 7 + ix + 3; if (x >= 56) x -= 56;
    return (size_t)((b * 56 + y) * 56 + x);
}

// ---------------- fused prep+gather: disjoint block ranges (independent outputs) ----------------
__global__ __launch_bounds__(256) void prep_gather(const float* __restrict__ xin,
                            unsigned short* __restrict__ xw,
                            const float* __restrict__ qkvw, const float* __restrict__ projw,
                            const float* __restrict__ rel_table,
                            unsigned short* __restrict__ wq, unsigned short* __restrict__ wp,
                            float* __restrict__ btt2) {
    const int blk = blockIdx.x;
    if (blk < 18816) {
        int idx = blk * 256 + threadIdx.x;   // one float4 per thread
        int row = idx / 96, c4 = (idx - row * 96) * 4;
        const float4 v = *(const float4*)(xin + row_to_pixel(row) * CCH + c4);
        ushort4 o;
        o.x = f2bf(v.x); o.y = f2bf(v.y); o.z = f2bf(v.z); o.w = f2bf(v.w);
        *(ushort4*)(xw + (size_t)row * CCH + c4) = o;
        return;
    }
    int i = (blk - 18816) * 256 + threadIdx.x;
    if (i < 3 * CCH * CCH) wq[i] = f2bf(qkvw[i]);
    if (i < CCH * CCH) wp[i] = f2bf(projw[i]);
    if (i < 4 * NHEADS * 16 * 64) {            // one float4 entry per thread
        int cls = i / (NHEADS * 16 * 64);
        int rem = i - cls * (NHEADS * 16 * 64);
        int h = rem / (16 * 64);
        int rem2 = rem - h * (16 * 64);
        int rb = rem2 >> 6, cj = rem2 & 63;
        int jreg = 0;
        if (cj < NTOK) {
            int jy = cj / 7, jx = cj - jy * 7;
            int ry = (cls & 2) ? ((jy < 4) ? 1 : 2) : 0;
            int rx = (cls & 1) ? ((jx < 4) ? 1 : 2) : 0;
            jreg = ry * 3 + rx;
        }
        float4 o;
        float* po = (float*)&o;
#pragma unroll
        for (int rr = 0; rr < 4; ++rr) {
            int ri = rb * 4 + rr;
            float v = -1e30f;
            if (ri < NTOK && cj < NTOK) {
                int iy = ri / 7, ix = ri - iy * 7;
                int jy = cj / 7, jx = cj - jy * 7;
                int idx = (iy - jy + 6) * 13 + (ix - jx + 6);
                v = rel_table[idx * NHEADS + h];
                int ry = (cls & 2) ? ((iy < 4) ? 1 : 2) : 0;
                int rx = (cls & 1) ? ((ix < 4) ? 1 : 2) : 0;
                if (ry * 3 + rx != jreg) v -= 100.f;
            }
            po[rr] = v;
        }
        *(float4*)&btt2[(size_t)i * 4] = o;
    }
}

// ---------------- QKV GEMM: 256x128 tile (R2 geometry), single-barrier 2-phase loop
// (T3 minimum recipe): STAGE(t+1) -> compute(t) -> vmcnt(0)+barrier. 12 barriers vs 24. ----------------
__global__ __launch_bounds__(512) void qkv_gemm(const unsigned short* __restrict__ xw,
        const unsigned short* __restrict__ wq, const float* __restrict__ qkv_bias,
        unsigned short* __restrict__ qb, unsigned short* __restrict__ kb,
        unsigned short* __restrict__ vb) {
    __shared__ unsigned short As[2][256 * 32];
    __shared__ unsigned short Bs[2][128 * 32];
    const int tid = threadIdx.x;
    // bijective XCD-chunk remap: nwg=1764, q=220, r=4 (m204 variant), col-fastest
    const int bid = blockIdx.x;
    const int xcd = bid & 7;
    const int base = (xcd < 4) ? xcd * 221 : (4 * 221 + (xcd - 4) * 220);
    const int swz = base + (bid >> 3);
    const int rb = swz / 9, cb = swz - rb * 9;
    const int row0 = rb * 256;
    const int col0 = cb * 128;
    const int lane = tid & 63, wv = tid >> 6;   // 8 waves
    const int wm = wv >> 1, wn = wv & 1;        // 4M x 2N, wave tile 64x64
    const int l15 = lane & 15, g = lane >> 4;

    // staging: per wave 2 A-loads (32 rows) + 1 B-load (16 rows); chunk swizzle f(row)=(row>>1)&3
    const int lrow = lane >> 2;                  // 0..15
    const int lc = lane & 3;                     // 16B chunk within 64B K-slice
    const int scs = ((lc ^ ((lrow >> 1) & 3)) * 8);   // pre-swizzled source chunk
    const unsigned short* gA0 = xw + (size_t)(row0 + wv * 32 + lrow) * CCH + scs;
    const unsigned short* gA1 = gA0 + (size_t)16 * CCH;
    const unsigned short* gB0 = wq + (size_t)(col0 + wv * 16 + lrow) * CCH + scs;
    // fragment-read chunk: rows read are 16*k + l15 -> f = (l15>>1)&3 (constant per lane)
    const int rc = (g ^ ((l15 >> 1) & 3)) * 8;

    f32x4 acc[4][4];
#pragma unroll
    for (int i = 0; i < 4; ++i)
#pragma unroll
        for (int j = 0; j < 4; ++j) acc[i][j] = (f32x4){0.f, 0.f, 0.f, 0.f};

    // prologue: stage tile 0 into buf 0, drain, sync
    g2lds16(gA0, &As[0][wv * 1024]);
    g2lds16(gA1, &As[0][wv * 1024 + 512]);
    g2lds16(gB0, &Bs[0][wv * 512]);
    WAITVM_BAR(0);

#pragma unroll
    for (int kk = 0; kk < 12; ++kk) {
        const int cur = kk & 1;
        if (kk < 11) {   // STAGE(t+1) early: flight spans the whole compute body
            const int nxt = cur ^ 1;
            g2lds16(gA0 + (kk + 1) * 32, &As[nxt][wv * 1024]);
            g2lds16(gA1 + (kk + 1) * 32, &As[nxt][wv * 1024 + 512]);
            g2lds16(gB0 + (kk + 1) * 32, &Bs[nxt][wv * 512]);
        }
        bf16x8 af[4], bfv[4];
#pragma unroll
        for (int mt = 0; mt < 4; ++mt)
            af[mt] = *(const bf16x8*)&As[cur][(wm * 64 + mt * 16 + l15) * 32 + rc];
#pragma unroll
        for (int nt = 0; nt < 4; ++nt)
            bfv[nt] = *(const bf16x8*)&Bs[cur][(wn * 64 + nt * 16 + l15) * 32 + rc];
#pragma unroll
        for (int mt = 0; mt < 4; ++mt)
#pragma unroll
            for (int nt = 0; nt < 4; ++nt)
                acc[mt][nt] = __builtin_amdgcn_mfma_f32_16x16x32_bf16(af[mt], bfv[nt], acc[mt][nt], 0, 0, 0);
        if (kk < 11) WAITVM_BAR(0);   // single sync point: tile t+1 landed AND all reads of cur done
    }

    // epilogue (R7 form — keeps VGPR at 64): + bias; q scaled; coalesced [inst][tok][dim]
    const float SCALE = 0.17677669529663687f;
#pragma unroll
    for (int nt = 0; nt < 4; ++nt) {
        int col = col0 + wn * 64 + nt * 16 + l15;
        float bias = qkv_bias[col];
        int which = col / CCH;
        int rem = col - which * CCH;
        int h = rem >> 5, d = rem & 31;
        unsigned short* dstb = (which == 0) ? qb : ((which == 1) ? kb : vb);
        float scl = (which == 0) ? SCALE : 1.0f;
#pragma unroll
        for (int mt = 0; mt < 4; ++mt) {
#pragma unroll
            for (int rr = 0; rr < 4; ++rr) {
                int row = row0 + wm * 64 + mt * 16 + g * 4 + rr;
                int w2 = row / 49, n2 = row - w2 * 49;
                size_t inst = (size_t)(w2 * NHEADS + h);
                float v = (acc[mt][nt][rr] + bias) * scl;
                dstb[(inst * NTOK + n2) * HDIM + d] = f2bf(v);
            }
        }
    }
}

// ---------------- attention: one wave per (window, head); V via swizzled LDS ----------------
__global__ __launch_bounds__(256) void attn_kernel(const unsigned short* __restrict__ qbuf,
        const unsigned short* __restrict__ kbuf, const unsigned short* __restrict__ vbuf,
        const float* __restrict__ btt2, unsigned short* __restrict__ ao) {
    __shared__ unsigned short Ps[4][64 * PSTR];
    __shared__ unsigned short Vt[4][32 * 64];   // [d][tok] with XOR-swizzled tok
    const int tid = threadIdx.x;
    const int lane = tid & 63, wv = tid >> 6;
    const int inst = blockIdx.x * 4 + wv;
    const int w = inst / NHEADS, h = inst - w * NHEADS;
    const int l15 = lane & 15, g = lane >> 4;
    const unsigned short* qp = qbuf + (size_t)inst * (NTOK * HDIM);
    const unsigned short* kp = kbuf + (size_t)inst * (NTOK * HDIM);
    const unsigned short* vp = vbuf + (size_t)inst * (NTOK * HDIM);

    const bf16x8 zero8 = {0, 0, 0, 0, 0, 0, 0, 0};
    // early V prefetch (T14): 4x16B; masked zero for tok>=49 (NaN-safe)
    bf16x8 vpre[4];
#pragma unroll
    for (int p = 0; p < 4; ++p) {
        int e0 = (p * 64 + lane) * 8;           // 8 elems share one tok (e0 8-aligned)
        int tok = e0 >> 5;
        vpre[p] = (tok < NTOK) ? *(const bf16x8*)&vp[e0] : zero8;
    }

    bf16x8 aq[4], bk[4];
#pragma unroll
    for (int mt = 0; mt < 4; ++mt) {
        int row = mt * 16 + l15;
        aq[mt] = (row < NTOK) ? *(const bf16x8*)&qp[row * HDIM + g * 8] : zero8;
    }
#pragma unroll
    for (int nt = 0; nt < 4; ++nt) {
        int colk = nt * 16 + l15;
        bk[nt] = (colk < NTOK) ? *(const bf16x8*)&kp[colk * HDIM + g * 8] : zero8;
    }
    f32x4 s[4][4];
#pragma unroll
    for (int mt = 0; mt < 4; ++mt)
#pragma unroll
        for (int nt = 0; nt < 4; ++nt)
            s[mt][nt] = __builtin_amdgcn_mfma_f32_16x16x32_bf16(aq[mt], bk[nt], (f32x4){0.f, 0.f, 0.f, 0.f}, 0, 0, 0);

    // write V to swizzled LDS transpose while QK^T/softmax proceed
    {
        unsigned short* vt = Vt[wv];
#pragma unroll
        for (int p = 0; p < 4; ++p) {
            int e0 = (p * 64 + lane) * 8;
            int tok = e0 >> 5, d0 = e0 & 31;
#pragma unroll
            for (int j = 0; j < 8; ++j) {
                int d = d0 + j;
                vt[d * 64 + (tok ^ ((d & 7) << 3))] = (unsigned short)vpre[p][j];
            }
        }
    }

    // logits: (pre-scaled q)K^T + fused bias/mask table; coalesced float4 loads
    const int wimg = w & 63;
    const int wy = wimg >> 3, wx = wimg & 7;
    const int wcls = (((wy == 7) ? 2 : 0) | ((wx == 7) ? 1 : 0));
    const float4* bt4 = (const float4*)btt2 + ((size_t)(wcls * NHEADS + h)) * (16 * 64);

    float inv[4][4];
#pragma unroll
    for (int mt = 0; mt < 4; ++mt) {
        float4 bias4[4];
#pragma unroll
        for (int nt = 0; nt < 4; ++nt)
            bias4[nt] = bt4[(mt * 4 + g) * 64 + nt * 16 + l15];
#pragma unroll
        for (int rr = 0; rr < 4; ++rr) {
#pragma unroll
            for (int nt = 0; nt < 4; ++nt) {
                float bb = (rr == 0) ? bias4[nt].x : (rr == 1) ? bias4[nt].y : (rr == 2) ? bias4[nt].z : bias4[nt].w;
                s[mt][nt][rr] += bb;
            }
            // row softmax (16-lane butterfly)
            float m = fmaxf(fmaxf(s[mt][0][rr], s[mt][1][rr]), fmaxf(s[mt][2][rr], s[mt][3][rr]));
            m = fmaxf(m, __shfl_xor(m, 1));
            m = fmaxf(m, __shfl_xor(m, 2));
            m = fmaxf(m, __shfl_xor(m, 4));
            m = fmaxf(m, __shfl_xor(m, 8));
            float sum = 0.f;
#pragma unroll
            for (int nt = 0; nt < 4; ++nt) {
                float p = __expf(s[mt][nt][rr] - m);
                s[mt][nt][rr] = p;
                sum += p;
            }
            sum += __shfl_xor(sum, 1);
            sum += __shfl_xor(sum, 2);
            sum += __shfl_xor(sum, 4);
            sum += __shfl_xor(sum, 8);
            inv[mt][rr] = 1.0f / sum;
        }
    }
    // P -> LDS (re-fragment for PV)
    unsigned short* ps = Ps[wv];
#pragma unroll
    for (int mt = 0; mt < 4; ++mt)
#pragma unroll
        for (int nt = 0; nt < 4; ++nt)
#pragma unroll
            for (int rr = 0; rr < 4; ++rr)
                ps[(mt * 16 + g * 4 + rr) * PSTR + nt * 16 + l15] = f2bf(s[mt][nt][rr]);

    f32x4 o[4][2];
#pragma unroll
    for (int mt = 0; mt < 4; ++mt)
#pragma unroll
        for (int dt = 0; dt < 2; ++dt) o[mt][dt] = (f32x4){0.f, 0.f, 0.f, 0.f};

    const unsigned short* vt = Vt[wv];
#pragma unroll
    for (int kt = 0; kt < 2; ++kt) {
        bf16x8 ap[4];
#pragma unroll
        for (int mt = 0; mt < 4; ++mt)
            ap[mt] = *(const bf16x8*)&ps[(mt * 16 + l15) * PSTR + kt * 32 + g * 8];
#pragma unroll
        for (int dt = 0; dt < 2; ++dt) {
            const int d = dt * 16 + l15;
            const int cb = kt * 32 + g * 8;
            bf16x8 bv = *(const bf16x8*)&vt[d * 64 + (cb ^ ((d & 7) << 3))];
#pragma unroll
            for (int mt = 0; mt < 4; ++mt)
                o[mt][dt] = __builtin_amdgcn_mfma_f32_16x16x32_bf16(ap[mt], bv, o[mt][dt], 0, 0, 0);
        }
    }
    // write attn-out [M=50176][384] bf16
#pragma unroll
    for (int mt = 0; mt < 4; ++mt)
#pragma unroll
        for (int dt = 0; dt < 2; ++dt)
#pragma unroll
            for (int rr = 0; rr < 4; ++rr) {
                int row = mt * 16 + g * 4 + rr;
                if (row < NTOK) {
                    float val = o[mt][dt][rr] * inv[mt][rr];
                    ao[((size_t)(w * NTOK + row)) * CCH + h * HDIM + dt * 16 + l15] = f2bf(val);
                }
            }
}

// ---------------- proj GEMM: 128x128 tile, single-barrier 2-phase loop, fused scatter ----------------
__global__ __launch_bounds__(256) void proj_gemm(const unsigned short* __restrict__ ain,
        const unsigned short* __restrict__ wp, const float* __restrict__ proj_bias,
        float* __restrict__ out) {
    __shared__ unsigned short As[2][128 * 32];
    __shared__ unsigned short Bs[2][128 * 32];
    const int tid = threadIdx.x;
    const int row0 = blockIdx.x * 128;
    const int col0 = blockIdx.y * 128;
    const int lane = tid & 63, wv = tid >> 6;
    const int wm = wv >> 1, wn = wv & 1;
    const int l15 = lane & 15, g = lane >> 4;

    const int srow = wv * 16 + (lane >> 2);               // group1 = +64, same f
    const int scs = (((lane & 3) ^ ((srow >> 1) & 3)) * 8);   // pre-swizzled source chunk
    const unsigned short* gA0 = ain + (size_t)(row0 + srow) * CCH + scs;
    const unsigned short* gA1 = gA0 + (size_t)64 * CCH;
    const unsigned short* gB0 = wp + (size_t)(col0 + srow) * CCH + scs;
    const unsigned short* gB1 = gB0 + (size_t)64 * CCH;
    const int rc = (g ^ ((l15 >> 1) & 3)) * 8;            // swizzled fragment-read chunk

    f32x4 acc[4][4];
#pragma unroll
    for (int i = 0; i < 4; ++i)
#pragma unroll
        for (int j = 0; j < 4; ++j) acc[i][j] = (f32x4){0.f, 0.f, 0.f, 0.f};

    g2lds16(gA0, &As[0][wv * 512]);
    g2lds16(gA1, &As[0][wv * 512 + 2048]);
    g2lds16(gB0, &Bs[0][wv * 512]);
    g2lds16(gB1, &Bs[0][wv * 512 + 2048]);
    WAITVM_BAR(0);

#pragma unroll
    for (int kk = 0; kk < 12; ++kk) {
        const int cur = kk & 1;
        if (kk < 11) {   // STAGE(t+1) early
            const int nxt = cur ^ 1;
            g2lds16(gA0 + (kk + 1) * 32, &As[nxt][wv * 512]);
            g2lds16(gA1 + (kk + 1) * 32, &As[nxt][wv * 512 + 2048]);
            g2lds16(gB0 + (kk + 1) * 32, &Bs[nxt][wv * 512]);
            g2lds16(gB1 + (kk + 1) * 32, &Bs[nxt][wv * 512 + 2048]);
        }
        bf16x8 af[4], bfv[4];
#pragma unroll
        for (int mt = 0; mt < 4; ++mt)
            af[mt] = *(const bf16x8*)&As[cur][(wm * 64 + mt * 16 + l15) * 32 + rc];
#pragma unroll
        for (int nt = 0; nt < 4; ++nt)
            bfv[nt] = *(const bf16x8*)&Bs[cur][(wn * 64 + nt * 16 + l15) * 32 + rc];
#pragma unroll
        for (int mt = 0; mt < 4; ++mt)
#pragma unroll
            for (int nt = 0; nt < 4; ++nt)
                acc[mt][nt] = __builtin_amdgcn_mfma_f32_16x16x32_bf16(af[mt], bfv[nt], acc[mt][nt], 0, 0, 0);
        if (kk < 11) WAITVM_BAR(0);
    }
#pragma unroll
    for (int nt = 0; nt < 4; ++nt) {
        int col = col0 + wn * 64 + nt * 16 + l15;
        float bias = proj_bias[col];
#pragma unroll
        for (int mt = 0; mt < 4; ++mt) {
#pragma unroll
            for (int rr = 0; rr < 4; ++rr) {
                int row = row0 + wm * 64 + mt * 16 + g * 4 + rr;
                out[row_to_pixel(row) * CCH + col] = acc[mt][nt][rr] + bias;
            }
        }
    }
}

extern "C" void kernel_launch(void* const* d_in, const int* in_sizes, int n_in,
                              void* d_out, int out_size, void* d_ws, size_t ws_size,
                              hipStream_t stream) {
    const float* x     = (const float*)d_in[0];
    const float* qkvw  = (const float*)d_in[1];
    const float* qkvb  = (const float*)d_in[2];
    const float* projw = (const float*)d_in[3];
    const float* projb = (const float*)d_in[4];
    const float* rel   = (const float*)d_in[5];
    float* out = (float*)d_out;

    char* ws = (char*)d_ws;
    unsigned short* wqb = (unsigned short*)(ws);                       // 884736 B
    unsigned short* wpb = (unsigned short*)(ws + 884736);              // 294912 B
    float* btt2         = (float*)(ws + 884736 + 294912);              // 786432 B
    const size_t off  = 2097152;                                       // aligned past tables
    const size_t bufb = 38535168ull;                                   // 50176*384*2
    unsigned short* qb  = (unsigned short*)(ws + off);
    unsigned short* kb  = (unsigned short*)(ws + off + bufb);
    unsigned short* vb  = (unsigned short*)(ws + off + 2 * bufb);
    unsigned short* ao  = (unsigned short*)(ws + off + 3 * bufb);
    unsigned short* xw  = ao;   // alias: xw dead once qkv_gemm finishes, before attn writes ao

    prep_gather<<<20544, 256, 0, stream>>>(x, xw, qkvw, projw, rel, wqb, wpb, btt2);
    qkv_gemm<<<1764, 512, 0, stream>>>(xw, wqb, qkvb, qb, kb, vb);
    attn_kernel<<<3072, 256, 0, stream>>>(qb, kb, vb, btt2, ao);
    proj_gemm<<<dim3(392, 3), 256, 0, stream>>>(ao, wpb, projb, out);
}

// Round 7
// 163.556 us; speedup vs baseline: 1.4586x; 1.0606x over previous
//
#include <hip/hip_runtime.h>

#define CCH 384
#define NHEADS 12
#define HDIM 32
#define NTOK 49
#define NWIN 1024
#define MROWS 50176
#define PSTR 72   // padded LDS stride for P tile (attn)

typedef __attribute__((ext_vector_type(8))) short bf16x8;
typedef __attribute__((ext_vector_type(4))) float f32x4;

#define WAITVM_BAR(N) asm volatile("s_waitcnt vmcnt(" #N ")\n\ts_barrier" ::: "memory")
#define BAR() asm volatile("s_barrier" ::: "memory")

__device__ __forceinline__ unsigned short f2bf(float f) {
    unsigned u = __builtin_bit_cast(unsigned, f);
    u += 0x7FFFu + ((u >> 16) & 1u);
    return (unsigned short)(u >> 16);
}

// async global -> LDS, 16B per lane. lds base must be wave-uniform.
__device__ __forceinline__ void g2lds16(const unsigned short* g, unsigned short* l) {
    __builtin_amdgcn_global_load_lds(
        (const __attribute__((address_space(1))) unsigned int*)g,
        (__attribute__((address_space(3))) unsigned int*)l,
        16, 0, 0);
}

// row -> source/dest pixel (roll by shift=3 folded in; same map both directions)
__device__ __forceinline__ size_t row_to_pixel(int r) {
    int wlin = r / 49, n = r - wlin * 49;
    int b = wlin >> 6, wimg = wlin & 63;
    int wy = wimg >> 3, wx = wimg & 7;
    int iy = n / 7, ix = n - iy * 7;
    int y = wy * 7 + iy + 3; if (y >= 56) y -= 56;
    int x = wx * 7 + ix + 3; if (x >= 56) x -= 56;
    return (size_t)((b * 56 + y) * 56 + x);
}

// ---------------- fused prep+gather: disjoint block ranges (independent outputs) ----------------
__global__ __launch_bounds__(256) void prep_gather(const float* __restrict__ xin,
                            unsigned short* __restrict__ xw,
                            const float* __restrict__ qkvw, const float* __restrict__ projw,
                            const float* __restrict__ rel_table,
                            unsigned short* __restrict__ wq, unsigned short* __restrict__ wp,
                            float* __restrict__ btt2) {
    const int blk = blockIdx.x;
    if (blk < 18816) {
        int idx = blk * 256 + threadIdx.x;   // one float4 per thread
        int row = idx / 96, c4 = (idx - row * 96) * 4;
        const float4 v = *(const float4*)(xin + row_to_pixel(row) * CCH + c4);
        ushort4 o;
        o.x = f2bf(v.x); o.y = f2bf(v.y); o.z = f2bf(v.z); o.w = f2bf(v.w);
        *(ushort4*)(xw + (size_t)row * CCH + c4) = o;
        return;
    }
    int i = (blk - 18816) * 256 + threadIdx.x;
    if (i < 3 * CCH * CCH) wq[i] = f2bf(qkvw[i]);
    if (i < CCH * CCH) wp[i] = f2bf(projw[i]);
    if (i < 4 * NHEADS * 16 * 64) {            // one float4 entry per thread
        int cls = i / (NHEADS * 16 * 64);
        int rem = i - cls * (NHEADS * 16 * 64);
        int h = rem / (16 * 64);
        int rem2 = rem - h * (16 * 64);
        int rb = rem2 >> 6, cj = rem2 & 63;
        int jreg = 0;
        if (cj < NTOK) {
            int jy = cj / 7, jx = cj - jy * 7;
            int ry = (cls & 2) ? ((jy < 4) ? 1 : 2) : 0;
            int rx = (cls & 1) ? ((jx < 4) ? 1 : 2) : 0;
            jreg = ry * 3 + rx;
        }
        float4 o;
        float* po = (float*)&o;
#pragma unroll
        for (int rr = 0; rr < 4; ++rr) {
            int ri = rb * 4 + rr;
            float v = -1e30f;
            if (ri < NTOK && cj < NTOK) {
                int iy = ri / 7, ix = ri - iy * 7;
                int jy = cj / 7, jx = cj - jy * 7;
                int idx = (iy - jy + 6) * 13 + (ix - jx + 6);
                v = rel_table[idx * NHEADS + h];
                int ry = (cls & 2) ? ((iy < 4) ? 1 : 2) : 0;
                int rx = (cls & 1) ? ((ix < 4) ? 1 : 2) : 0;
                if (ry * 3 + rx != jreg) v -= 100.f;
            }
            po[rr] = v;
        }
        *(float4*)&btt2[(size_t)i * 4] = o;
    }
}

// ---------------- QKV GEMM: 256x128 tile, single-barrier 2-phase loop (R6 form) ----------------
__global__ __launch_bounds__(512) void qkv_gemm(const unsigned short* __restrict__ xw,
        const unsigned short* __restrict__ wq, const float* __restrict__ qkv_bias,
        unsigned short* __restrict__ qb, unsigned short* __restrict__ kb,
        unsigned short* __restrict__ vb) {
    __shared__ unsigned short As[2][256 * 32];
    __shared__ unsigned short Bs[2][128 * 32];
    const int tid = threadIdx.x;
    // bijective XCD-chunk remap: nwg=1764, q=220, r=4 (m204 variant), col-fastest
    const int bid = blockIdx.x;
    const int xcd = bid & 7;
    const int base = (xcd < 4) ? xcd * 221 : (4 * 221 + (xcd - 4) * 220);
    const int swz = base + (bid >> 3);
    const int rb = swz / 9, cb = swz - rb * 9;
    const int row0 = rb * 256;
    const int col0 = cb * 128;
    const int lane = tid & 63, wv = tid >> 6;   // 8 waves
    const int wm = wv >> 1, wn = wv & 1;        // 4M x 2N, wave tile 64x64
    const int l15 = lane & 15, g = lane >> 4;

    // staging: per wave 2 A-loads (32 rows) + 1 B-load (16 rows); chunk swizzle f(row)=(row>>1)&3
    const int lrow = lane >> 2;                  // 0..15
    const int lc = lane & 3;                     // 16B chunk within 64B K-slice
    const int scs = ((lc ^ ((lrow >> 1) & 3)) * 8);   // pre-swizzled source chunk
    const unsigned short* gA0 = xw + (size_t)(row0 + wv * 32 + lrow) * CCH + scs;
    const unsigned short* gA1 = gA0 + (size_t)16 * CCH;
    const unsigned short* gB0 = wq + (size_t)(col0 + wv * 16 + lrow) * CCH + scs;
    // fragment-read chunk: rows read are 16*k + l15 -> f = (l15>>1)&3 (constant per lane)
    const int rc = (g ^ ((l15 >> 1) & 3)) * 8;

    f32x4 acc[4][4];
#pragma unroll
    for (int i = 0; i < 4; ++i)
#pragma unroll
        for (int j = 0; j < 4; ++j) acc[i][j] = (f32x4){0.f, 0.f, 0.f, 0.f};

    // prologue: stage tile 0 into buf 0, drain, sync
    g2lds16(gA0, &As[0][wv * 1024]);
    g2lds16(gA1, &As[0][wv * 1024 + 512]);
    g2lds16(gB0, &Bs[0][wv * 512]);
    WAITVM_BAR(0);

#pragma unroll
    for (int kk = 0; kk < 12; ++kk) {
        const int cur = kk & 1;
        if (kk < 11) {   // STAGE(t+1) early: flight spans the whole compute body
            const int nxt = cur ^ 1;
            g2lds16(gA0 + (kk + 1) * 32, &As[nxt][wv * 1024]);
            g2lds16(gA1 + (kk + 1) * 32, &As[nxt][wv * 1024 + 512]);
            g2lds16(gB0 + (kk + 1) * 32, &Bs[nxt][wv * 512]);
        }
        bf16x8 af[4], bfv[4];
#pragma unroll
        for (int mt = 0; mt < 4; ++mt)
            af[mt] = *(const bf16x8*)&As[cur][(wm * 64 + mt * 16 + l15) * 32 + rc];
#pragma unroll
        for (int nt = 0; nt < 4; ++nt)
            bfv[nt] = *(const bf16x8*)&Bs[cur][(wn * 64 + nt * 16 + l15) * 32 + rc];
#pragma unroll
        for (int mt = 0; mt < 4; ++mt)
#pragma unroll
            for (int nt = 0; nt < 4; ++nt)
                acc[mt][nt] = __builtin_amdgcn_mfma_f32_16x16x32_bf16(af[mt], bfv[nt], acc[mt][nt], 0, 0, 0);
        if (kk < 11) WAITVM_BAR(0);   // single sync point: tile t+1 landed AND all reads of cur done
    }

    // epilogue (R7 form — keeps VGPR at 64): + bias; q scaled; coalesced [inst][tok][dim]
    const float SCALE = 0.17677669529663687f;
#pragma unroll
    for (int nt = 0; nt < 4; ++nt) {
        int col = col0 + wn * 64 + nt * 16 + l15;
        float bias = qkv_bias[col];
        int which = col / CCH;
        int rem = col - which * CCH;
        int h = rem >> 5, d = rem & 31;
        unsigned short* dstb = (which == 0) ? qb : ((which == 1) ? kb : vb);
        float scl = (which == 0) ? SCALE : 1.0f;
#pragma unroll
        for (int mt = 0; mt < 4; ++mt) {
#pragma unroll
            for (int rr = 0; rr < 4; ++rr) {
                int row = row0 + wm * 64 + mt * 16 + g * 4 + rr;
                int w2 = row / 49, n2 = row - w2 * 49;
                size_t inst = (size_t)(w2 * NHEADS + h);
                float v = (acc[mt][nt][rr] + bias) * scl;
                dstb[(inst * NTOK + n2) * HDIM + d] = f2bf(v);
            }
        }
    }
}

// ---------------- attention: one wave per (window, head); V via swizzled LDS ----------------
__global__ __launch_bounds__(256) void attn_kernel(const unsigned short* __restrict__ qbuf,
        const unsigned short* __restrict__ kbuf, const unsigned short* __restrict__ vbuf,
        const float* __restrict__ btt2, unsigned short* __restrict__ ao) {
    __shared__ unsigned short Ps[4][64 * PSTR];
    __shared__ unsigned short Vt[4][32 * 64];   // [d][tok] with XOR-swizzled tok
    const int tid = threadIdx.x;
    const int lane = tid & 63, wv = tid >> 6;
    const int inst = blockIdx.x * 4 + wv;
    const int w = inst / NHEADS, h = inst - w * NHEADS;
    const int l15 = lane & 15, g = lane >> 4;
    const unsigned short* qp = qbuf + (size_t)inst * (NTOK * HDIM);
    const unsigned short* kp = kbuf + (size_t)inst * (NTOK * HDIM);
    const unsigned short* vp = vbuf + (size_t)inst * (NTOK * HDIM);

    const bf16x8 zero8 = {0, 0, 0, 0, 0, 0, 0, 0};
    // early V prefetch (T14): 4x16B; masked zero for tok>=49 (NaN-safe)
    bf16x8 vpre[4];
#pragma unroll
    for (int p = 0; p < 4; ++p) {
        int e0 = (p * 64 + lane) * 8;           // 8 elems share one tok (e0 8-aligned)
        int tok = e0 >> 5;
        vpre[p] = (tok < NTOK) ? *(const bf16x8*)&vp[e0] : zero8;
    }

    bf16x8 aq[4], bk[4];
#pragma unroll
    for (int mt = 0; mt < 4; ++mt) {
        int row = mt * 16 + l15;
        aq[mt] = (row < NTOK) ? *(const bf16x8*)&qp[row * HDIM + g * 8] : zero8;
    }
#pragma unroll
    for (int nt = 0; nt < 4; ++nt) {
        int colk = nt * 16 + l15;
        bk[nt] = (colk < NTOK) ? *(const bf16x8*)&kp[colk * HDIM + g * 8] : zero8;
    }
    f32x4 s[4][4];
#pragma unroll
    for (int mt = 0; mt < 4; ++mt)
#pragma unroll
        for (int nt = 0; nt < 4; ++nt)
            s[mt][nt] = __builtin_amdgcn_mfma_f32_16x16x32_bf16(aq[mt], bk[nt], (f32x4){0.f, 0.f, 0.f, 0.f}, 0, 0, 0);

    // write V to swizzled LDS transpose while QK^T/softmax proceed
    {
        unsigned short* vt = Vt[wv];
#pragma unroll
        for (int p = 0; p < 4; ++p) {
            int e0 = (p * 64 + lane) * 8;
            int tok = e0 >> 5, d0 = e0 & 31;
#pragma unroll
            for (int j = 0; j < 8; ++j) {
                int d = d0 + j;
                vt[d * 64 + (tok ^ ((d & 7) << 3))] = (unsigned short)vpre[p][j];
            }
        }
    }

    // logits: (pre-scaled q)K^T + fused bias/mask table; coalesced float4 loads
    const int wimg = w & 63;
    const int wy = wimg >> 3, wx = wimg & 7;
    const int wcls = (((wy == 7) ? 2 : 0) | ((wx == 7) ? 1 : 0));
    const float4* bt4 = (const float4*)btt2 + ((size_t)(wcls * NHEADS + h)) * (16 * 64);

    float inv[4][4];
#pragma unroll
    for (int mt = 0; mt < 4; ++mt) {
        float4 bias4[4];
#pragma unroll
        for (int nt = 0; nt < 4; ++nt)
            bias4[nt] = bt4[(mt * 4 + g) * 64 + nt * 16 + l15];
#pragma unroll
        for (int rr = 0; rr < 4; ++rr) {
#pragma unroll
            for (int nt = 0; nt < 4; ++nt) {
                float bb = (rr == 0) ? bias4[nt].x : (rr == 1) ? bias4[nt].y : (rr == 2) ? bias4[nt].z : bias4[nt].w;
                s[mt][nt][rr] += bb;
            }
            // row softmax (16-lane butterfly)
            float m = fmaxf(fmaxf(s[mt][0][rr], s[mt][1][rr]), fmaxf(s[mt][2][rr], s[mt][3][rr]));
            m = fmaxf(m, __shfl_xor(m, 1));
            m = fmaxf(m, __shfl_xor(m, 2));
            m = fmaxf(m, __shfl_xor(m, 4));
            m = fmaxf(m, __shfl_xor(m, 8));
            float sum = 0.f;
#pragma unroll
            for (int nt = 0; nt < 4; ++nt) {
                float p = __expf(s[mt][nt][rr] - m);
                s[mt][nt][rr] = p;
                sum += p;
            }
            sum += __shfl_xor(sum, 1);
            sum += __shfl_xor(sum, 2);
            sum += __shfl_xor(sum, 4);
            sum += __shfl_xor(sum, 8);
            inv[mt][rr] = 1.0f / sum;
        }
    }
    // P -> LDS (re-fragment for PV)
    unsigned short* ps = Ps[wv];
#pragma unroll
    for (int mt = 0; mt < 4; ++mt)
#pragma unroll
        for (int nt = 0; nt < 4; ++nt)
#pragma unroll
            for (int rr = 0; rr < 4; ++rr)
                ps[(mt * 16 + g * 4 + rr) * PSTR + nt * 16 + l15] = f2bf(s[mt][nt][rr]);

    f32x4 o[4][2];
#pragma unroll
    for (int mt = 0; mt < 4; ++mt)
#pragma unroll
        for (int dt = 0; dt < 2; ++dt) o[mt][dt] = (f32x4){0.f, 0.f, 0.f, 0.f};

    const unsigned short* vt = Vt[wv];
#pragma unroll
    for (int kt = 0; kt < 2; ++kt) {
        bf16x8 ap[4];
#pragma unroll
        for (int mt = 0; mt < 4; ++mt)
            ap[mt] = *(const bf16x8*)&ps[(mt * 16 + l15) * PSTR + kt * 32 + g * 8];
#pragma unroll
        for (int dt = 0; dt < 2; ++dt) {
            const int d = dt * 16 + l15;
            const int cb = kt * 32 + g * 8;
            bf16x8 bv = *(const bf16x8*)&vt[d * 64 + (cb ^ ((d & 7) << 3))];
#pragma unroll
            for (int mt = 0; mt < 4; ++mt)
                o[mt][dt] = __builtin_amdgcn_mfma_f32_16x16x32_bf16(ap[mt], bv, o[mt][dt], 0, 0, 0);
        }
    }
    // write attn-out [M=50176][384] bf16
#pragma unroll
    for (int mt = 0; mt < 4; ++mt)
#pragma unroll
        for (int dt = 0; dt < 2; ++dt)
#pragma unroll
            for (int rr = 0; rr < 4; ++rr) {
                int row = mt * 16 + g * 4 + rr;
                if (row < NTOK) {
                    float val = o[mt][dt][rr] * inv[mt][rr];
                    ao[((size_t)(w * NTOK + row)) * CCH + h * HDIM + dt * 16 + l15] = f2bf(val);
                }
            }
}

// ---------------- proj GEMM: 128x128 tile, single-barrier 2-phase loop, fused scatter.
// NEW: 1-D grid, col-fastest + bijective XCD chunking (1176 = 8*147): the 3 col-blocks
// sharing an A-row-panel are dispatch-adjacent -> A fetched from HBM once, not 3x. ----------------
__global__ __launch_bounds__(256) void proj_gemm(const unsigned short* __restrict__ ain,
        const unsigned short* __restrict__ wp, const float* __restrict__ proj_bias,
        float* __restrict__ out) {
    __shared__ unsigned short As[2][128 * 32];
    __shared__ unsigned short Bs[2][128 * 32];
    const int tid = threadIdx.x;
    const int bid = blockIdx.x;                       // 1176 blocks
    const int swz = (bid & 7) * 147 + (bid >> 3);     // exact bijection (1176 % 8 == 0)
    const int rbk = swz / 3, cbk = swz - rbk * 3;     // col-fastest
    const int row0 = rbk * 128;
    const int col0 = cbk * 128;
    const int lane = tid & 63, wv = tid >> 6;
    const int wm = wv >> 1, wn = wv & 1;
    const int l15 = lane & 15, g = lane >> 4;

    const int srow = wv * 16 + (lane >> 2);               // group1 = +64, same f
    const int scs = (((lane & 3) ^ ((srow >> 1) & 3)) * 8);   // pre-swizzled source chunk
    const unsigned short* gA0 = ain + (size_t)(row0 + srow) * CCH + scs;
    const unsigned short* gA1 = gA0 + (size_t)64 * CCH;
    const unsigned short* gB0 = wp + (size_t)(col0 + srow) * CCH + scs;
    const unsigned short* gB1 = gB0 + (size_t)64 * CCH;
    const int rc = (g ^ ((l15 >> 1) & 3)) * 8;            // swizzled fragment-read chunk

    f32x4 acc[4][4];
#pragma unroll
    for (int i = 0; i < 4; ++i)
#pragma unroll
        for (int j = 0; j < 4; ++j) acc[i][j] = (f32x4){0.f, 0.f, 0.f, 0.f};

    g2lds16(gA0, &As[0][wv * 512]);
    g2lds16(gA1, &As[0][wv * 512 + 2048]);
    g2lds16(gB0, &Bs[0][wv * 512]);
    g2lds16(gB1, &Bs[0][wv * 512 + 2048]);
    WAITVM_BAR(0);

#pragma unroll
    for (int kk = 0; kk < 12; ++kk) {
        const int cur = kk & 1;
        if (kk < 11) {   // STAGE(t+1) early
            const int nxt = cur ^ 1;
            g2lds16(gA0 + (kk + 1) * 32, &As[nxt][wv * 512]);
            g2lds16(gA1 + (kk + 1) * 32, &As[nxt][wv * 512 + 2048]);
            g2lds16(gB0 + (kk + 1) * 32, &Bs[nxt][wv * 512]);
            g2lds16(gB1 + (kk + 1) * 32, &Bs[nxt][wv * 512 + 2048]);
        }
        bf16x8 af[4], bfv[4];
#pragma unroll
        for (int mt = 0; mt < 4; ++mt)
            af[mt] = *(const bf16x8*)&As[cur][(wm * 64 + mt * 16 + l15) * 32 + rc];
#pragma unroll
        for (int nt = 0; nt < 4; ++nt)
            bfv[nt] = *(const bf16x8*)&Bs[cur][(wn * 64 + nt * 16 + l15) * 32 + rc];
#pragma unroll
        for (int mt = 0; mt < 4; ++mt)
#pragma unroll
            for (int nt = 0; nt < 4; ++nt)
                acc[mt][nt] = __builtin_amdgcn_mfma_f32_16x16x32_bf16(af[mt], bfv[nt], acc[mt][nt], 0, 0, 0);
        if (kk < 11) WAITVM_BAR(0);
    }
#pragma unroll
    for (int nt = 0; nt < 4; ++nt) {
        int col = col0 + wn * 64 + nt * 16 + l15;
        float bias = proj_bias[col];
#pragma unroll
        for (int mt = 0; mt < 4; ++mt) {
#pragma unroll
            for (int rr = 0; rr < 4; ++rr) {
                int row = row0 + wm * 64 + mt * 16 + g * 4 + rr;
                out[row_to_pixel(row) * CCH + col] = acc[mt][nt][rr] + bias;
            }
        }
    }
}

extern "C" void kernel_launch(void* const* d_in, const int* in_sizes, int n_in,
                              void* d_out, int out_size, void* d_ws, size_t ws_size,
                              hipStream_t stream) {
    const float* x     = (const float*)d_in[0];
    const float* qkvw  = (const float*)d_in[1];
    const float* qkvb  = (const float*)d_in[2];
    const float* projw = (const float*)d_in[3];
    const float* projb = (const float*)d_in[4];
    const float* rel   = (const float*)d_in[5];
    float* out = (float*)d_out;

    char* ws = (char*)d_ws;
    unsigned short* wqb = (unsigned short*)(ws);                       // 884736 B
    unsigned short* wpb = (unsigned short*)(ws + 884736);              // 294912 B
    float* btt2         = (float*)(ws + 884736 + 294912);              // 786432 B
    const size_t off  = 2097152;                                       // aligned past tables
    const size_t bufb = 38535168ull;                                   // 50176*384*2
    unsigned short* qb  = (unsigned short*)(ws + off);
    unsigned short* kb  = (unsigned short*)(ws + off + bufb);
    unsigned short* vb  = (unsigned short*)(ws + off + 2 * bufb);
    unsigned short* ao  = (unsigned short*)(ws + off + 3 * bufb);
    unsigned short* xw  = ao;   // alias: xw dead once qkv_gemm finishes, before attn writes ao

    prep_gather<<<20544, 256, 0, stream>>>(x, xw, qkvw, projw, rel, wqb, wpb, btt2);
    qkv_gemm<<<1764, 512, 0, stream>>>(xw, wqb, qkvb, qb, kb, vb);
    attn_kernel<<<3072, 256, 0, stream>>>(qb, kb, vb, btt2, ao);
    proj_gemm<<<1176, 256, 0, stream>>>(ao, wpb, projb, out);
}